// Round 1
// 252.687 us; speedup vs baseline: 1.1111x; 1.1111x over previous
//
#include <hip/hip_runtime.h>
#include <hip/hip_bf16.h>
#include <math.h>

#define DIM      1024
#define D_STATE  64
#define D_CONV   4
#define N_HEADS  8
#define D_INNER  2048
#define HEAD_DIM 256
#define NPROJ    4232      // 2048 + 2048 + 8 + 64 + 64
#define BATCH    2
#define SEQ      1024
#define M_ROWS   (BATCH * SEQ)   // 2048
#define OFF_Z    0
#define OFF_XC   2048
#define OFF_DT   4096
#define OFF_B    4104
#define OFF_C    4168

#define CHUNK    64
#define N_CHUNK  (SEQ / CHUNK)    // 16
#define STATE_PER_BH (HEAD_DIM * D_STATE)   // 16384 floats

#define NPROJ_PAD 4352            // 34 * 128 (GEMM1 grid only; B rows guarded)
#define PADT 72                   // padded u16 row pitch for 64-wide LDS tiles

typedef unsigned short u16;
typedef _Float16 f16x8 __attribute__((ext_vector_type(8)));
typedef float    f32x4 __attribute__((ext_vector_type(4)));

// fp16 helpers (RNE via v_cvt_f16_f32; denorms enabled by default on gfx950)
__device__ __forceinline__ u16 f2h(float f) {
    _Float16 h = (_Float16)f;
    return __builtin_bit_cast(u16, h);
}
__device__ __forceinline__ float h2f(u16 u) {
    return (float)__builtin_bit_cast(_Float16, u);
}

__device__ __forceinline__ void load_lds16(const void* g, void* l) {
    __builtin_amdgcn_global_load_lds((const __attribute__((address_space(1))) unsigned int*)g,
                                     (__attribute__((address_space(3))) unsigned int*)l,
                                     16, 0, 0);
}

__device__ __forceinline__ float softplus_f(float v) {
    return (v > 20.f) ? v : log1pf(expf(v));
}

// ---------------------------------------------------------------------------
// merged cast: segment 0 (x) -> split fp16 hi+lo; segment 1 (in_proj_w) ->
// single fp16 (weights stay single: GEMM computes A_fp32 @ fp16(B) exactly).
// ---------------------------------------------------------------------------
__global__ __launch_bounds__(256) void cast_split2_kernel(
        const float* __restrict__ s0, u16* __restrict__ h0, u16* __restrict__ l0, int n0,
        const float* __restrict__ s1, u16* __restrict__ h1, int n1) {
    int i4 = (blockIdx.x * 256 + threadIdx.x) * 4;
    if (i4 < n0) {
        float4 v = *(const float4*)&s0[i4];
        ushort4 h, l;
        h.x = f2h(v.x); h.y = f2h(v.y); h.z = f2h(v.z); h.w = f2h(v.w);
        l.x = f2h(v.x - h2f(h.x));
        l.y = f2h(v.y - h2f(h.y));
        l.z = f2h(v.z - h2f(h.z));
        l.w = f2h(v.w - h2f(h.w));
        *(ushort4*)&h0[i4] = h;
        *(ushort4*)&l0[i4] = l;
    } else {
        i4 -= n0;
        if (i4 >= n1) return;
        float4 v = *(const float4*)&s1[i4];
        ushort4 h;
        h.x = f2h(v.x); h.y = f2h(v.y); h.z = f2h(v.z); h.w = f2h(v.w);
        *(ushort4*)&h1[i4] = h;
    }
}

// single fp16 cast (out_proj_w)
__global__ __launch_bounds__(256) void cast_h_kernel(const float* __restrict__ src,
                                                     u16* __restrict__ hi, int n) {
    int i4 = (blockIdx.x * 256 + threadIdx.x) * 4;
    if (i4 >= n) return;
    float4 v = *(const float4*)&src[i4];
    ushort4 h;
    h.x = f2h(v.x); h.y = f2h(v.y); h.z = f2h(v.z); h.w = f2h(v.w);
    *(ushort4*)&hi[i4] = h;
}

// ---------------------------------------------------------------------------
// split-fp16 MFMA GEMM: C = A @ B^T, A ~ Ah+Al (fp16 hi/lo), B ~ fp16.
// acc += Ah*B + Al*B  == fp32(A) @ fp16(B), fp32 accum.  2 MFMA per tile
// (was 3 with bf16 split) -> 2/3 the matrix-pipe work, 3/4 the staging.
// BM=128 x BN tile, BK=32, 256 thr (2x2 waves).
// B rows guarded by NrowsB; stores by Nstore. Optional split-K via gridDim.z.
// ---------------------------------------------------------------------------
template<int BN>
__global__ __launch_bounds__(256) void gemm_mfma2(const u16* __restrict__ Ah,
                                                  const u16* __restrict__ Al,
                                                  const u16* __restrict__ Bh,
                                                  float* __restrict__ C,
                                                  int K, int ldc, int Nstore,
                                                  int NrowsB, size_t zstride) {
    __shared__ u16 AsH[128 * 32];
    __shared__ u16 AsL[128 * 32];
    __shared__ u16 Bs [BN * 32];

    const int tid  = threadIdx.x;
    const int wave = tid >> 6;
    const int lane = tid & 63;
    const int fr   = lane & 15;
    const int kc   = lane >> 4;
    const int m0   = blockIdx.y * 128;
    const int n0   = blockIdx.x * BN;
    const int wm   = (wave & 1) * 64;
    const int wn   = (wave >> 1) * (BN / 2);

    const int kPer = K / gridDim.z;
    const int kBeg = blockIdx.z * kPer;
    C += (size_t)blockIdx.z * zstride;

    f32x4 acc[4][BN / 32];
#pragma unroll
    for (int i = 0; i < 4; ++i)
#pragma unroll
        for (int j = 0; j < BN / 32; ++j) acc[i][j] = (f32x4)0.f;

    for (int k0 = kBeg; k0 < kBeg + kPer; k0 += 32) {
        __syncthreads();
#pragma unroll
        for (int q = 0; q < 2; ++q) {
            int s = wave * 128 + q * 64 + lane;
            int r = s >> 2, pc = s & 3;
            int gc = pc ^ ((r >> 1) & 3);
            size_t goff = (size_t)(m0 + r) * K + k0 + gc * 8;
            load_lds16(Ah + goff, &AsH[(wave * 128 + q * 64) * 8]);
            load_lds16(Al + goff, &AsL[(wave * 128 + q * 64) * 8]);
        }
#pragma unroll
        for (int q = 0; q < BN / 64; ++q) {
            int s = wave * BN + q * 64 + lane;
            int r = s >> 2, pc = s & 3;
            int gc = pc ^ ((r >> 1) & 3);
            if (n0 + r < NrowsB) {   // OOB rows: stale LDS, results never stored
                size_t goff = (size_t)(n0 + r) * K + k0 + gc * 8;
                load_lds16(Bh + goff, &Bs[(wave * BN + q * 64) * 8]);
            }
        }
        __syncthreads();

        f16x8 afh[4], afl[4];
#pragma unroll
        for (int i = 0; i < 4; ++i) {
            int r = wm + i * 16 + fr;
            int off = r * 32 + (kc ^ ((r >> 1) & 3)) * 8;
            afh[i] = *(const f16x8*)&AsH[off];
            afl[i] = *(const f16x8*)&AsL[off];
        }
        f16x8 bf[BN / 32];
#pragma unroll
        for (int j = 0; j < BN / 32; ++j) {
            int r = wn + j * 16 + fr;
            int off = r * 32 + (kc ^ ((r >> 1) & 3)) * 8;
            bf[j] = *(const f16x8*)&Bs[off];
        }
#pragma unroll
        for (int i = 0; i < 4; ++i)
#pragma unroll
            for (int j = 0; j < BN / 32; ++j) {
                acc[i][j] = __builtin_amdgcn_mfma_f32_16x16x32_f16(afh[i], bf[j], acc[i][j], 0, 0, 0);
                acc[i][j] = __builtin_amdgcn_mfma_f32_16x16x32_f16(afl[i], bf[j], acc[i][j], 0, 0, 0);
            }
    }

    // epilogue: C/D layout col=lane&15, row=(lane>>4)*4+reg  [m89/m91]
    const int row0 = m0 + wm + (lane >> 4) * 4;
    const int colb = n0 + wn + fr;
#pragma unroll
    for (int i = 0; i < 4; ++i)
#pragma unroll
        for (int j = 0; j < BN / 32; ++j) {
            int col = colb + j * 16;
            if (col < Nstore) {
#pragma unroll
                for (int t = 0; t < 4; ++t)
                    C[(size_t)(row0 + i * 16 + t) * ldc + col] = acc[i][j][t];
            }
        }
}

// ---------------------------------------------------------------------------
// split-K=2 partial reduce
// ---------------------------------------------------------------------------
__global__ __launch_bounds__(256) void reduce2_kernel(const float* __restrict__ p,
                                                      float* __restrict__ out, int n) {
    int i4 = (blockIdx.x * 256 + threadIdx.x) * 4;
    float4 a = *(const float4*)&p[i4];
    float4 b = *(const float4*)&p[(size_t)n + i4];
    *(float4*)&out[i4] = make_float4(a.x + b.x, a.y + b.y, a.z + b.z, a.w + b.w);
}

// ---------------------------------------------------------------------------
// depthwise causal conv (k=4) + SiLU -> xh (fp16); first 64 blocks: dt/a_bar.
// ---------------------------------------------------------------------------
__global__ __launch_bounds__(256) void conv_silu_kernel(const float* __restrict__ zx,
                                                        const float* __restrict__ conv_w,
                                                        const float* __restrict__ conv_b,
                                                        const float* __restrict__ dt_bias,
                                                        const float* __restrict__ A_log,
                                                        u16* __restrict__ xh,
                                                        float* __restrict__ abar) {
    int idx = blockIdx.x * 256 + threadIdx.x;
    int c = idx & (D_INNER - 1);
    int m = idx >> 11;
    int l = m & (SEQ - 1);
    float acc = conv_b[c];
#pragma unroll
    for (int k = 0; k < D_CONV; ++k) {
        int lj = l + k - (D_CONV - 1);
        if (lj >= 0)
            acc = fmaf(zx[(size_t)(m + k - (D_CONV - 1)) * NPROJ + OFF_XC + c],
                       conv_w[c * D_CONV + k], acc);
    }
    xh[idx] = f2h(acc / (1.f + expf(-acc)));

    if (blockIdx.x < (M_ROWS * N_HEADS) / 256) {
        int di = blockIdx.x * 256 + threadIdx.x;
        int h = di & (N_HEADS - 1);
        int dm = di >> 3;
        float v = zx[(size_t)dm * NPROJ + OFF_DT + h] + dt_bias[h];
        abar[di] = expf(softplus_f(v) * -expf(A_log[h]));
    }
}

// ---------------------------------------------------------------------------
// PASS 1 (SSD/MFMA): per (b,h,chunk,dq-64-slice):
//   G = C@B^T; P[t][s] = exp(A(SD[t]-SD[s]))*G (s<=t);
//   Y_local = P@X; S_c = (w2*B)^T @ X.
// All matmuls via 16x16x32 f16 MFMA (fp16 operands: 2^-12 rel rounding,
// 8x tighter than the previous bf16 path).  X read as fp16 from xh.
// ---------------------------------------------------------------------------
__global__ __launch_bounds__(256) void scan_local_mfma(const float* __restrict__ zx,
                                                       const u16* __restrict__ xh,
                                                       const float* __restrict__ dt_bias,
                                                       const float* __restrict__ A_log,
                                                       float* __restrict__ yscan,
                                                       float* __restrict__ Sloc) {
    const int blk = blockIdx.x;                 // 0..1023
    const int dq = blk & 3;
    const int c  = (blk >> 2) & (N_CHUNK - 1);
    const int bh = blk >> 6;
    const int hh = bh & (N_HEADS - 1);
    const int b  = bh >> 3;
    const int t    = threadIdx.x;
    const int wave = t >> 6;
    const int lane = t & 63;
    const int fr   = lane & 15;
    const int quad = lane >> 4;

    __shared__ float SDs[64];
    __shared__ u16 Ct [64 * PADT];
    __shared__ u16 Bt [64 * PADT];
    __shared__ u16 BwT[64 * PADT];
    __shared__ u16 Ps [64 * PADT];
    __shared__ u16 XsT[64 * PADT];              // [d][t] for this 64-d slice

    const int m0   = b * SEQ + c * CHUNK;
    const int xcol = hh * HEAD_DIM + dq * 64;
    const float Ahd = -expf(A_log[hh]);
    const float dtb = dt_bias[hh];

    // dt inclusive prefix sum (wave 0)
    if (t < 64) {
        float d = softplus_f(zx[(size_t)(m0 + t) * NPROJ + OFF_DT + hh] + dtb);
#pragma unroll
        for (int off = 1; off < 64; off <<= 1) {
            float o = __shfl_up(d, off);
            if (lane >= off) d += o;
        }
        SDs[t] = d;
    }
    __syncthreads();
    const float SD63 = SDs[63];

    // stage B, C, Bw^T, X^T tiles (fp32->fp16 / fp16 passthrough)
#pragma unroll
    for (int i = 0; i < 16; ++i) {
        int idx = t + i * 256;
        int r = idx >> 6, n = idx & 63;
        size_t rowz = (size_t)(m0 + r) * NPROJ;
        float bv = zx[rowz + OFF_B + n];
        float cv = zx[rowz + OFF_C + n];
        Bt[r * PADT + n] = f2h(bv);
        Ct[r * PADT + n] = f2h(cv);
        float w2 = expf(Ahd * (SD63 - SDs[r]));
        BwT[n * PADT + r] = f2h(bv * w2);
        // X^T: d = n index here reused
        XsT[n * PADT + r] = xh[(size_t)(m0 + r) * D_INNER + xcol + n];
    }
    __syncthreads();

    const int tm0 = wave * 16;

    // G = C@B^T  (this wave's 16 t-rows x 64 s)
    f32x4 g[4];
#pragma unroll
    for (int j = 0; j < 4; ++j) g[j] = (f32x4)0.f;
#pragma unroll
    for (int kk = 0; kk < 2; ++kk) {
        f16x8 af = *(const f16x8*)&Ct[(tm0 + fr) * PADT + kk * 32 + quad * 8];
#pragma unroll
        for (int j = 0; j < 4; ++j) {
            f16x8 bf = *(const f16x8*)&Bt[(j * 16 + fr) * PADT + kk * 32 + quad * 8];
            g[j] = __builtin_amdgcn_mfma_f32_16x16x32_f16(af, bf, g[j], 0, 0, 0);
        }
    }
    // mask + decay -> Ps (same-wave rows only; no barrier needed)
    {
        int trow = tm0 + quad * 4;
#pragma unroll
        for (int j = 0; j < 4; ++j) {
#pragma unroll
            for (int reg = 0; reg < 4; ++reg) {
                int tt = trow + reg, ss = j * 16 + fr;
                float val = 0.f;
                if (ss <= tt) val = expf(Ahd * (SDs[tt] - SDs[ss])) * g[j][reg];
                Ps[tt * PADT + ss] = f2h(val);
            }
        }
    }

    // Y_local = P @ X   (a = Ps rows[t], b = XsT rows[d])
    f32x4 ya[4];
#pragma unroll
    for (int j = 0; j < 4; ++j) ya[j] = (f32x4)0.f;
#pragma unroll
    for (int kk = 0; kk < 2; ++kk) {
        f16x8 af = *(const f16x8*)&Ps[(tm0 + fr) * PADT + kk * 32 + quad * 8];
#pragma unroll
        for (int j = 0; j < 4; ++j) {
            f16x8 bf = *(const f16x8*)&XsT[(j * 16 + fr) * PADT + kk * 32 + quad * 8];
            ya[j] = __builtin_amdgcn_mfma_f32_16x16x32_f16(af, bf, ya[j], 0, 0, 0);
        }
    }
#pragma unroll
    for (int j = 0; j < 4; ++j)
#pragma unroll
        for (int reg = 0; reg < 4; ++reg) {
            int tt = tm0 + quad * 4 + reg;
            int dd = j * 16 + fr;
            yscan[(size_t)(m0 + tt) * D_INNER + xcol + dd] = ya[j][reg];
        }

    // S_c = Bw^T @ X  (a = BwT rows[n], b = XsT rows[d]) -> Sloc[n][d]
    f32x4 sa[4];
#pragma unroll
    for (int j = 0; j < 4; ++j) sa[j] = (f32x4)0.f;
#pragma unroll
    for (int kk = 0; kk < 2; ++kk) {
        f16x8 af = *(const f16x8*)&BwT[(tm0 + fr) * PADT + kk * 32 + quad * 8];
#pragma unroll
        for (int j = 0; j < 4; ++j) {
            f16x8 bf = *(const f16x8*)&XsT[(j * 16 + fr) * PADT + kk * 32 + quad * 8];
            sa[j] = __builtin_amdgcn_mfma_f32_16x16x32_f16(af, bf, sa[j], 0, 0, 0);
        }
    }
    size_t sbase = (size_t)(bh * N_CHUNK + c) * STATE_PER_BH;
#pragma unroll
    for (int j = 0; j < 4; ++j)
#pragma unroll
        for (int reg = 0; reg < 4; ++reg) {
            int nn = tm0 + quad * 4 + reg;
            int dd = j * 16 + fr;
            Sloc[sbase + (size_t)nn * HEAD_DIM + dq * 64 + dd] = sa[j][reg];
        }
}

// ---------------------------------------------------------------------------
// PASS 2: inter-chunk recurrence in place on Sloc -> H_init(c). (layout-flat)
// ---------------------------------------------------------------------------
__global__ __launch_bounds__(256) void scan_combine_kernel(const float* __restrict__ abar,
                                                           float* __restrict__ Sloc) {
    const int blk = blockIdx.x;
    const int ds = blk & 15;
    const int bh = blk >> 4;
    const int hh = bh & (N_HEADS - 1);
    const int b  = bh >> 3;
    const int t  = threadIdx.x;

    __shared__ float PS[N_CHUNK];
    if (t < N_CHUNK) {
        float p = 1.f;
        int mbase = b * SEQ + t * CHUNK;
        for (int j = 0; j < CHUNK; ++j)
            p *= abar[(mbase + j) * N_HEADS + hh];
        PS[t] = p;
    }
    __syncthreads();

    float H[4] = {0.f, 0.f, 0.f, 0.f};
    for (int c = 0; c < N_CHUNK; ++c) {
        size_t base = (size_t)(bh * N_CHUNK + c) * STATE_PER_BH + ds * 1024 + t;
        float Sv[4];
#pragma unroll
        for (int i = 0; i < 4; ++i) Sv[i] = Sloc[base + i * 256];
#pragma unroll
        for (int i = 0; i < 4; ++i) Sloc[base + i * 256] = H[i];
        float P = PS[c];
#pragma unroll
        for (int i = 0; i < 4; ++i) H[i] = fmaf(P, H[i], Sv[i]);
    }
}

// ---------------------------------------------------------------------------
// PASS 3 (MFMA): Y[t][d] += cum[t] * (C @ H)  with H from Sloc[n][d].
// ---------------------------------------------------------------------------
__global__ __launch_bounds__(256) void scan_corr_mfma(const float* __restrict__ zx,
                                                      const float* __restrict__ dt_bias,
                                                      const float* __restrict__ A_log,
                                                      const float* __restrict__ Hini,
                                                      float* __restrict__ yscan) {
    const int blk = blockIdx.x;
    const int dq = blk & 3;
    const int c  = (blk >> 2) & (N_CHUNK - 1);
    const int bh = blk >> 6;
    const int hh = bh & (N_HEADS - 1);
    const int b  = bh >> 3;
    const int t    = threadIdx.x;
    const int wave = t >> 6;
    const int lane = t & 63;
    const int fr   = lane & 15;
    const int quad = lane >> 4;

    __shared__ float SDs[64];
    __shared__ u16 Ct [64 * PADT];
    __shared__ u16 Hdn[64 * PADT];              // [d][n] fp16

    const int m0   = b * SEQ + c * CHUNK;
    const int xcol = hh * HEAD_DIM + dq * 64;
    const float Ahd = -expf(A_log[hh]);
    const float dtb = dt_bias[hh];

    if (t < 64) {
        float d = softplus_f(zx[(size_t)(m0 + t) * NPROJ + OFF_DT + hh] + dtb);
#pragma unroll
        for (int off = 1; off < 64; off <<= 1) {
            float o = __shfl_up(d, off);
            if (lane >= off) d += o;
        }
        SDs[t] = d;
    }

    size_t hbase = (size_t)(bh * N_CHUNK + c) * STATE_PER_BH;
#pragma unroll
    for (int i = 0; i < 16; ++i) {
        int idx = t + i * 256;
        int r = idx >> 6, n = idx & 63;       // r: row index (t or n), n: col
        Ct[r * PADT + n] = f2h(zx[(size_t)(m0 + r) * NPROJ + OFF_C + n]);
        // H: read [n=r][d=n-col] coalesced, store transposed [d][n]
        Hdn[n * PADT + r] = f2h(Hini[hbase + (size_t)r * HEAD_DIM + dq * 64 + n]);
    }
    __syncthreads();

    const int tm0 = wave * 16;
    f32x4 ya[4];
#pragma unroll
    for (int j = 0; j < 4; ++j) ya[j] = (f32x4)0.f;
#pragma unroll
    for (int kk = 0; kk < 2; ++kk) {
        f16x8 af = *(const f16x8*)&Ct[(tm0 + fr) * PADT + kk * 32 + quad * 8];
#pragma unroll
        for (int j = 0; j < 4; ++j) {
            f16x8 bf = *(const f16x8*)&Hdn[(j * 16 + fr) * PADT + kk * 32 + quad * 8];
            ya[j] = __builtin_amdgcn_mfma_f32_16x16x32_f16(af, bf, ya[j], 0, 0, 0);
        }
    }
#pragma unroll
    for (int reg = 0; reg < 4; ++reg) {
        int tt = tm0 + quad * 4 + reg;
        float cum = expf(Ahd * SDs[tt]);
#pragma unroll
        for (int j = 0; j < 4; ++j) {
            int dd = j * 16 + fr;
            size_t off = (size_t)(m0 + tt) * D_INNER + xcol + dd;
            yscan[off] += cum * ya[j][reg];
        }
    }
}

// ---------------------------------------------------------------------------
// y = (yscan + D*x) * silu(z); RMSNorm; emits fp16 hi/lo split. xh is fp16.
// ---------------------------------------------------------------------------
__global__ __launch_bounds__(256) void gate_norm_kernel(const float* __restrict__ zx,
                                                        const u16* __restrict__ xh,
                                                        const float* __restrict__ Dp,
                                                        const float* __restrict__ nw,
                                                        const float* __restrict__ y,
                                                        u16* __restrict__ ybf_h,
                                                        u16* __restrict__ ybf_l) {
    const int m = blockIdx.x;
    const int t = threadIdx.x;
    const size_t rowz = (size_t)m * NPROJ;
    const size_t rowy = (size_t)m * D_INNER;

    float v[8];
    float ss = 0.f;
#pragma unroll
    for (int i = 0; i < 8; ++i) {
        int c = t + i * 256;
        float ys = fmaf(Dp[c >> 8], h2f(xh[rowy + c]), y[rowy + c]);
        float z  = zx[rowz + OFF_Z + c];
        float gated = ys * (z / (1.f + expf(-z)));
        v[i] = gated;
        ss += gated * gated;
    }
#pragma unroll
    for (int off = 1; off < 64; off <<= 1) ss += __shfl_xor(ss, off);

    __shared__ float red[4];
    if ((t & 63) == 0) red[t >> 6] = ss;
    __syncthreads();
    float tot = red[0] + red[1] + red[2] + red[3];
    float scale = 1.f / sqrtf(tot / (float)D_INNER + 1e-6f);

#pragma unroll
    for (int i = 0; i < 8; ++i) {
        int c = t + i * 256;
        float o = v[i] * scale * nw[c];
        u16 h = f2h(o);
        ybf_h[rowy + c] = h;
        ybf_l[rowy + c] = f2h(o - h2f(h));
    }
}

// ---------------------------------------------------------------------------
extern "C" void kernel_launch(void* const* d_in, const int* in_sizes, int n_in,
                              void* d_out, int out_size, void* d_ws, size_t ws_size,
                              hipStream_t stream) {
    const float* x         = (const float*)d_in[0];
    const float* in_proj_w = (const float*)d_in[1];
    const float* conv_w    = (const float*)d_in[2];
    const float* conv_b    = (const float*)d_in[3];
    const float* A_log     = (const float*)d_in[4];
    const float* D_param   = (const float*)d_in[5];
    const float* dt_bias   = (const float*)d_in[6];
    const float* norm_w    = (const float*)d_in[7];
    const float* out_proj_w= (const float*)d_in[8];
    float* out = (float*)d_out;

    // workspace layout (floats), total 76.96 MB (unchanged):
    //  zx  @0         8,667,136  | later pbuf (2x 2,097,152 fits)
    //  R1  @8667136   2,166,784  | xh(u16) -> wobf_h(u16)
    //  R2  @10833920  4,194,304  | xbf h+l -> ysc
    //  ab  @15028224     16,384
    //  R3  @15044608  4,194,304  | wibf_h -> Sloc -> ybf h+l
    float* ws  = (float*)d_ws;
    float* zx  = ws;
    float* R1  = zx + 8667136;
    float* R2  = R1 + 2166784;
    float* ab  = R2 + 4194304;
    float* R3  = ab + 16384;

    u16*  xh     = (u16*)R1;
    u16*  wobf_h = (u16*)R1;                            // reuses xh after last read
    u16*  xbf_h  = (u16*)R2;
    u16*  xbf_l  = xbf_h + (size_t)M_ROWS * DIM;
    float* ysc   = R2;
    u16*  wibf_h = (u16*)R3;
    float* Sloc  = R3;
    u16*  ybf_h  = (u16*)R3;
    u16*  ybf_l  = ybf_h + (size_t)M_ROWS * D_INNER;
    float* pbuf  = zx;

    // 0) casts for GEMM1: x -> split fp16, in_proj_w -> single fp16
    {
        int n0 = M_ROWS * DIM;              // 2,097,152
        int n1 = NPROJ * DIM;               // 4,333,568
        cast_split2_kernel<<<(n0 + n1) / 1024, 256, 0, stream>>>(
            x, xbf_h, xbf_l, n0, in_proj_w, wibf_h, n1);
    }

    // 1) zxBCdt = x @ in_proj_w^T  (2048 x 4232, K=1024)
    gemm_mfma2<128><<<dim3(NPROJ_PAD / 128, M_ROWS / 128, 1), 256, 0, stream>>>(
        xbf_h, xbf_l, wibf_h, zx, DIM, NPROJ, NPROJ, NPROJ, 0);

    // 2) conv + silu -> xh (fp16) + dt/a_bar -> ab
    conv_silu_kernel<<<(M_ROWS * D_INNER) / 256, 256, 0, stream>>>(
        zx, conv_w, conv_b, dt_bias, A_log, xh, ab);

    // 3) SSD chunked scan (MFMA passes 1 and 3)
    scan_local_mfma<<<BATCH * N_HEADS * N_CHUNK * 4, 256, 0, stream>>>(
        zx, xh, dt_bias, A_log, ysc, Sloc);
    scan_combine_kernel<<<BATCH * N_HEADS * 16, 256, 0, stream>>>(ab, Sloc);
    scan_corr_mfma<<<BATCH * N_HEADS * N_CHUNK * 4, 256, 0, stream>>>(
        zx, dt_bias, A_log, Sloc, ysc);

    // 4) gate + rmsnorm, emits split-fp16 y
    gate_norm_kernel<<<M_ROWS, 256, 0, stream>>>(
        zx, xh, D_param, norm_w, ysc, ybf_h, ybf_l);

    // 5) single fp16 cast for GEMM2 weights
    cast_h_kernel<<<(DIM * D_INNER) / 1024, 256, 0, stream>>>(
        out_proj_w, wobf_h, DIM * D_INNER);

    // 6) out = y @ out_proj_w^T  (2048 x 1024, K=2048), BN=64, split-K=2
    gemm_mfma2<64><<<dim3(DIM / 64, M_ROWS / 128, 2), 256, 0, stream>>>(
        ybf_h, ybf_l, wobf_h, pbuf, D_INNER, DIM, DIM, DIM,
        (size_t)M_ROWS * DIM);

    // 7) reduce partials -> out
    reduce2_kernel<<<(M_ROWS * DIM) / 1024, 256, 0, stream>>>(pbuf, out, M_ROWS * DIM);
}

// Round 3
// 224.817 us; speedup vs baseline: 1.2489x; 1.1240x over previous
//
#include <hip/hip_runtime.h>
#include <hip/hip_bf16.h>
#include <math.h>

#define DIM      1024
#define D_STATE  64
#define D_CONV   4
#define N_HEADS  8
#define D_INNER  2048
#define HEAD_DIM 256
#define NPROJ    4232      // 2048 + 2048 + 8 + 64 + 64
#define BATCH    2
#define SEQ      1024
#define M_ROWS   (BATCH * SEQ)   // 2048
#define OFF_Z    0
#define OFF_XC   2048
#define OFF_DT   4096
#define OFF_B    4104
#define OFF_C    4168

#define CHUNK    64
#define N_CHUNK  (SEQ / CHUNK)    // 16
#define STATE_PER_BH (HEAD_DIM * D_STATE)   // 16384 floats

#define NPROJ_PAD 4352            // 34 * 128 (GEMM1 grid only; B rows guarded)
#define PADT 72                   // padded u16 row pitch for 64-wide LDS tiles

typedef unsigned short u16;
typedef _Float16 f16x8 __attribute__((ext_vector_type(8)));
typedef float    f32x4 __attribute__((ext_vector_type(4)));

// fp16 helpers (RNE via v_cvt_f16_f32; denorms enabled by default on gfx950)
__device__ __forceinline__ u16 f2h(float f) {
    _Float16 h = (_Float16)f;
    return __builtin_bit_cast(u16, h);
}
__device__ __forceinline__ float h2f(u16 u) {
    return (float)__builtin_bit_cast(_Float16, u);
}

__device__ __forceinline__ void load_lds16(const void* g, void* l) {
    __builtin_amdgcn_global_load_lds((const __attribute__((address_space(1))) unsigned int*)g,
                                     (__attribute__((address_space(3))) unsigned int*)l,
                                     16, 0, 0);
}

__device__ __forceinline__ float softplus_f(float v) {
    return (v > 20.f) ? v : log1pf(expf(v));
}

// ---------------------------------------------------------------------------
// merged cast: segment 0 (x) and segment 1 (in_proj_w) -> single fp16.
// GEMM error from fp16 inputs (~2^-11 rel) is 10x below the scan's fp16
// noise floor (absmax 0.0156 measured), so no hi/lo split needed anywhere.
// ---------------------------------------------------------------------------
__global__ __launch_bounds__(256) void cast2_kernel(
        const float* __restrict__ s0, u16* __restrict__ h0, int n0,
        const float* __restrict__ s1, u16* __restrict__ h1, int n1) {
    int i4 = (blockIdx.x * 256 + threadIdx.x) * 4;
    const float* src; u16* dst;
    if (i4 < n0) {
        src = s0; dst = h0;
    } else {
        i4 -= n0;
        if (i4 >= n1) return;
        src = s1; dst = h1;
    }
    float4 v = *(const float4*)&src[i4];
    ushort4 h;
    h.x = f2h(v.x); h.y = f2h(v.y); h.z = f2h(v.z); h.w = f2h(v.w);
    *(ushort4*)&dst[i4] = h;
}

// single fp16 cast (out_proj_w)
__global__ __launch_bounds__(256) void cast_h_kernel(const float* __restrict__ src,
                                                     u16* __restrict__ hi, int n) {
    int i4 = (blockIdx.x * 256 + threadIdx.x) * 4;
    if (i4 >= n) return;
    float4 v = *(const float4*)&src[i4];
    ushort4 h;
    h.x = f2h(v.x); h.y = f2h(v.y); h.z = f2h(v.z); h.w = f2h(v.w);
    *(ushort4*)&hi[i4] = h;
}

// ---------------------------------------------------------------------------
// fp16 MFMA GEMM: C = A @ B^T, fp32 accum.  1 MFMA per tile (m97 structure:
// 16 MFMA + 4 global_load_lds + 8 ds_read_b128 per K-step).
// BM=128 x BN tile, BK=32, 256 thr (2x2 waves).
// B rows guarded by NrowsB; stores by Nstore. Optional split-K via gridDim.z.
// ---------------------------------------------------------------------------
template<int BN>
__global__ __launch_bounds__(256) void gemm_mfma1(const u16* __restrict__ Ah,
                                                  const u16* __restrict__ Bh,
                                                  float* __restrict__ C,
                                                  int K, int ldc, int Nstore,
                                                  int NrowsB, size_t zstride) {
    __shared__ u16 As[128 * 32];
    __shared__ u16 Bs[BN * 32];

    const int tid  = threadIdx.x;
    const int wave = tid >> 6;
    const int lane = tid & 63;
    const int fr   = lane & 15;
    const int kc   = lane >> 4;
    const int m0   = blockIdx.y * 128;
    const int n0   = blockIdx.x * BN;
    const int wm   = (wave & 1) * 64;
    const int wn   = (wave >> 1) * (BN / 2);

    const int kPer = K / gridDim.z;
    const int kBeg = blockIdx.z * kPer;
    C += (size_t)blockIdx.z * zstride;

    f32x4 acc[4][BN / 32];
#pragma unroll
    for (int i = 0; i < 4; ++i)
#pragma unroll
        for (int j = 0; j < BN / 32; ++j) acc[i][j] = (f32x4)0.f;

    for (int k0 = kBeg; k0 < kBeg + kPer; k0 += 32) {
        __syncthreads();
#pragma unroll
        for (int q = 0; q < 2; ++q) {
            int s = wave * 128 + q * 64 + lane;
            int r = s >> 2, pc = s & 3;
            int gc = pc ^ ((r >> 1) & 3);
            size_t goff = (size_t)(m0 + r) * K + k0 + gc * 8;
            load_lds16(Ah + goff, &As[(wave * 128 + q * 64) * 8]);
        }
#pragma unroll
        for (int q = 0; q < BN / 64; ++q) {
            int s = wave * BN + q * 64 + lane;
            int r = s >> 2, pc = s & 3;
            int gc = pc ^ ((r >> 1) & 3);
            if (n0 + r < NrowsB) {   // OOB rows: stale LDS, results never stored
                size_t goff = (size_t)(n0 + r) * K + k0 + gc * 8;
                load_lds16(Bh + goff, &Bs[(wave * BN + q * 64) * 8]);
            }
        }
        __syncthreads();

        f16x8 af[4];
#pragma unroll
        for (int i = 0; i < 4; ++i) {
            int r = wm + i * 16 + fr;
            int off = r * 32 + (kc ^ ((r >> 1) & 3)) * 8;
            af[i] = *(const f16x8*)&As[off];
        }
        f16x8 bf[BN / 32];
#pragma unroll
        for (int j = 0; j < BN / 32; ++j) {
            int r = wn + j * 16 + fr;
            int off = r * 32 + (kc ^ ((r >> 1) & 3)) * 8;
            bf[j] = *(const f16x8*)&Bs[off];
        }
#pragma unroll
        for (int i = 0; i < 4; ++i)
#pragma unroll
            for (int j = 0; j < BN / 32; ++j)
                acc[i][j] = __builtin_amdgcn_mfma_f32_16x16x32_f16(af[i], bf[j], acc[i][j], 0, 0, 0);
    }

    // epilogue: C/D layout col=lane&15, row=(lane>>4)*4+reg  [m89/m91]
    const int row0 = m0 + wm + (lane >> 4) * 4;
    const int colb = n0 + wn + fr;
#pragma unroll
    for (int i = 0; i < 4; ++i)
#pragma unroll
        for (int j = 0; j < BN / 32; ++j) {
            int col = colb + j * 16;
            if (col < Nstore) {
#pragma unroll
                for (int t = 0; t < 4; ++t)
                    C[(size_t)(row0 + i * 16 + t) * ldc + col] = acc[i][j][t];
            }
        }
}

// ---------------------------------------------------------------------------
// split-K=2 partial reduce
// ---------------------------------------------------------------------------
__global__ __launch_bounds__(256) void reduce2_kernel(const float* __restrict__ p,
                                                      float* __restrict__ out, int n) {
    int i4 = (blockIdx.x * 256 + threadIdx.x) * 4;
    float4 a = *(const float4*)&p[i4];
    float4 b = *(const float4*)&p[(size_t)n + i4];
    *(float4*)&out[i4] = make_float4(a.x + b.x, a.y + b.y, a.z + b.z, a.w + b.w);
}

// ---------------------------------------------------------------------------
// depthwise causal conv (k=4) + SiLU -> xh (fp16); first 64 blocks: dt/a_bar.
// ---------------------------------------------------------------------------
__global__ __launch_bounds__(256) void conv_silu_kernel(const float* __restrict__ zx,
                                                        const float* __restrict__ conv_w,
                                                        const float* __restrict__ conv_b,
                                                        const float* __restrict__ dt_bias,
                                                        const float* __restrict__ A_log,
                                                        u16* __restrict__ xh,
                                                        float* __restrict__ abar) {
    int idx = blockIdx.x * 256 + threadIdx.x;
    int c = idx & (D_INNER - 1);
    int m = idx >> 11;
    int l = m & (SEQ - 1);
    float acc = conv_b[c];
#pragma unroll
    for (int k = 0; k < D_CONV; ++k) {
        int lj = l + k - (D_CONV - 1);
        if (lj >= 0)
            acc = fmaf(zx[(size_t)(m + k - (D_CONV - 1)) * NPROJ + OFF_XC + c],
                       conv_w[c * D_CONV + k], acc);
    }
    xh[idx] = f2h(acc / (1.f + expf(-acc)));

    if (blockIdx.x < (M_ROWS * N_HEADS) / 256) {
        int di = blockIdx.x * 256 + threadIdx.x;
        int h = di & (N_HEADS - 1);
        int dm = di >> 3;
        float v = zx[(size_t)dm * NPROJ + OFF_DT + h] + dt_bias[h];
        abar[di] = expf(softplus_f(v) * -expf(A_log[h]));
    }
}

// ---------------------------------------------------------------------------
// PASS 1 (SSD/MFMA): per (b,h,chunk,dq-64-slice):
//   G = C@B^T; P[t][s] = exp(A(SD[t]-SD[s]))*G (s<=t);
//   Y_local = P@X; S_c = (w2*B)^T @ X.
// All matmuls via 16x16x32 f16 MFMA.  X read as fp16 from xh.
// ---------------------------------------------------------------------------
__global__ __launch_bounds__(256) void scan_local_mfma(const float* __restrict__ zx,
                                                       const u16* __restrict__ xh,
                                                       const float* __restrict__ dt_bias,
                                                       const float* __restrict__ A_log,
                                                       float* __restrict__ yscan,
                                                       float* __restrict__ Sloc) {
    const int blk = blockIdx.x;                 // 0..1023
    const int dq = blk & 3;
    const int c  = (blk >> 2) & (N_CHUNK - 1);
    const int bh = blk >> 6;
    const int hh = bh & (N_HEADS - 1);
    const int b  = bh >> 3;
    const int t    = threadIdx.x;
    const int wave = t >> 6;
    const int lane = t & 63;
    const int fr   = lane & 15;
    const int quad = lane >> 4;

    __shared__ float SDs[64];
    __shared__ u16 Ct [64 * PADT];
    __shared__ u16 Bt [64 * PADT];
    __shared__ u16 BwT[64 * PADT];
    __shared__ u16 Ps [64 * PADT];
    __shared__ u16 XsT[64 * PADT];              // [d][t] for this 64-d slice

    const int m0   = b * SEQ + c * CHUNK;
    const int xcol = hh * HEAD_DIM + dq * 64;
    const float Ahd = -expf(A_log[hh]);
    const float dtb = dt_bias[hh];

    // dt inclusive prefix sum (wave 0)
    if (t < 64) {
        float d = softplus_f(zx[(size_t)(m0 + t) * NPROJ + OFF_DT + hh] + dtb);
#pragma unroll
        for (int off = 1; off < 64; off <<= 1) {
            float o = __shfl_up(d, off);
            if (lane >= off) d += o;
        }
        SDs[t] = d;
    }
    __syncthreads();
    const float SD63 = SDs[63];

    // stage B, C, Bw^T, X^T tiles (fp32->fp16 / fp16 passthrough)
#pragma unroll
    for (int i = 0; i < 16; ++i) {
        int idx = t + i * 256;
        int r = idx >> 6, n = idx & 63;
        size_t rowz = (size_t)(m0 + r) * NPROJ;
        float bv = zx[rowz + OFF_B + n];
        float cv = zx[rowz + OFF_C + n];
        Bt[r * PADT + n] = f2h(bv);
        Ct[r * PADT + n] = f2h(cv);
        float w2 = expf(Ahd * (SD63 - SDs[r]));
        BwT[n * PADT + r] = f2h(bv * w2);
        // X^T: d = n index here reused
        XsT[n * PADT + r] = xh[(size_t)(m0 + r) * D_INNER + xcol + n];
    }
    __syncthreads();

    const int tm0 = wave * 16;

    // G = C@B^T  (this wave's 16 t-rows x 64 s)
    f32x4 g[4];
#pragma unroll
    for (int j = 0; j < 4; ++j) g[j] = (f32x4)0.f;
#pragma unroll
    for (int kk = 0; kk < 2; ++kk) {
        f16x8 af = *(const f16x8*)&Ct[(tm0 + fr) * PADT + kk * 32 + quad * 8];
#pragma unroll
        for (int j = 0; j < 4; ++j) {
            f16x8 bf = *(const f16x8*)&Bt[(j * 16 + fr) * PADT + kk * 32 + quad * 8];
            g[j] = __builtin_amdgcn_mfma_f32_16x16x32_f16(af, bf, g[j], 0, 0, 0);
        }
    }
    // mask + decay -> Ps (same-wave rows only; no barrier needed)
    {
        int trow = tm0 + quad * 4;
#pragma unroll
        for (int j = 0; j < 4; ++j) {
#pragma unroll
            for (int reg = 0; reg < 4; ++reg) {
                int tt = trow + reg, ss = j * 16 + fr;
                float val = 0.f;
                if (ss <= tt) val = expf(Ahd * (SDs[tt] - SDs[ss])) * g[j][reg];
                Ps[tt * PADT + ss] = f2h(val);
            }
        }
    }

    // Y_local = P @ X   (a = Ps rows[t], b = XsT rows[d])
    f32x4 ya[4];
#pragma unroll
    for (int j = 0; j < 4; ++j) ya[j] = (f32x4)0.f;
#pragma unroll
    for (int kk = 0; kk < 2; ++kk) {
        f16x8 af = *(const f16x8*)&Ps[(tm0 + fr) * PADT + kk * 32 + quad * 8];
#pragma unroll
        for (int j = 0; j < 4; ++j) {
            f16x8 bf = *(const f16x8*)&XsT[(j * 16 + fr) * PADT + kk * 32 + quad * 8];
            ya[j] = __builtin_amdgcn_mfma_f32_16x16x32_f16(af, bf, ya[j], 0, 0, 0);
        }
    }
#pragma unroll
    for (int j = 0; j < 4; ++j)
#pragma unroll
        for (int reg = 0; reg < 4; ++reg) {
            int tt = tm0 + quad * 4 + reg;
            int dd = j * 16 + fr;
            yscan[(size_t)(m0 + tt) * D_INNER + xcol + dd] = ya[j][reg];
        }

    // S_c = Bw^T @ X  (a = BwT rows[n], b = XsT rows[d]) -> Sloc[n][d]
    f32x4 sa[4];
#pragma unroll
    for (int j = 0; j < 4; ++j) sa[j] = (f32x4)0.f;
#pragma unroll
    for (int kk = 0; kk < 2; ++kk) {
        f16x8 af = *(const f16x8*)&BwT[(tm0 + fr) * PADT + kk * 32 + quad * 8];
#pragma unroll
        for (int j = 0; j < 4; ++j) {
            f16x8 bf = *(const f16x8*)&XsT[(j * 16 + fr) * PADT + kk * 32 + quad * 8];
            sa[j] = __builtin_amdgcn_mfma_f32_16x16x32_f16(af, bf, sa[j], 0, 0, 0);
        }
    }
    size_t sbase = (size_t)(bh * N_CHUNK + c) * STATE_PER_BH;
#pragma unroll
    for (int j = 0; j < 4; ++j)
#pragma unroll
        for (int reg = 0; reg < 4; ++reg) {
            int nn = tm0 + quad * 4 + reg;
            int dd = j * 16 + fr;
            Sloc[sbase + (size_t)nn * HEAD_DIM + dq * 64 + dd] = sa[j][reg];
        }
}

// ---------------------------------------------------------------------------
// PASS 2: inter-chunk recurrence in place on Sloc -> H_init(c). (layout-flat)
// ---------------------------------------------------------------------------
__global__ __launch_bounds__(256) void scan_combine_kernel(const float* __restrict__ abar,
                                                           float* __restrict__ Sloc) {
    const int blk = blockIdx.x;
    const int ds = blk & 15;
    const int bh = blk >> 4;
    const int hh = bh & (N_HEADS - 1);
    const int b  = bh >> 3;
    const int t  = threadIdx.x;

    __shared__ float PS[N_CHUNK];
    if (t < N_CHUNK) {
        float p = 1.f;
        int mbase = b * SEQ + t * CHUNK;
        for (int j = 0; j < CHUNK; ++j)
            p *= abar[(mbase + j) * N_HEADS + hh];
        PS[t] = p;
    }
    __syncthreads();

    float H[4] = {0.f, 0.f, 0.f, 0.f};
    for (int c = 0; c < N_CHUNK; ++c) {
        size_t base = (size_t)(bh * N_CHUNK + c) * STATE_PER_BH + ds * 1024 + t;
        float Sv[4];
#pragma unroll
        for (int i = 0; i < 4; ++i) Sv[i] = Sloc[base + i * 256];
#pragma unroll
        for (int i = 0; i < 4; ++i) Sloc[base + i * 256] = H[i];
        float P = PS[c];
#pragma unroll
        for (int i = 0; i < 4; ++i) H[i] = fmaf(P, H[i], Sv[i]);
    }
}

// ---------------------------------------------------------------------------
// PASS 3 (MFMA): Y[t][d] += cum[t] * (C @ H)  with H from Sloc[n][d].
// ---------------------------------------------------------------------------
__global__ __launch_bounds__(256) void scan_corr_mfma(const float* __restrict__ zx,
                                                      const float* __restrict__ dt_bias,
                                                      const float* __restrict__ A_log,
                                                      const float* __restrict__ Hini,
                                                      float* __restrict__ yscan) {
    const int blk = blockIdx.x;
    const int dq = blk & 3;
    const int c  = (blk >> 2) & (N_CHUNK - 1);
    const int bh = blk >> 6;
    const int hh = bh & (N_HEADS - 1);
    const int b  = bh >> 3;
    const int t    = threadIdx.x;
    const int wave = t >> 6;
    const int lane = t & 63;
    const int fr   = lane & 15;
    const int quad = lane >> 4;

    __shared__ float SDs[64];
    __shared__ u16 Ct [64 * PADT];
    __shared__ u16 Hdn[64 * PADT];              // [d][n] fp16

    const int m0   = b * SEQ + c * CHUNK;
    const int xcol = hh * HEAD_DIM + dq * 64;
    const float Ahd = -expf(A_log[hh]);
    const float dtb = dt_bias[hh];

    if (t < 64) {
        float d = softplus_f(zx[(size_t)(m0 + t) * NPROJ + OFF_DT + hh] + dtb);
#pragma unroll
        for (int off = 1; off < 64; off <<= 1) {
            float o = __shfl_up(d, off);
            if (lane >= off) d += o;
        }
        SDs[t] = d;
    }

    size_t hbase = (size_t)(bh * N_CHUNK + c) * STATE_PER_BH;
#pragma unroll
    for (int i = 0; i < 16; ++i) {
        int idx = t + i * 256;
        int r = idx >> 6, n = idx & 63;       // r: row index (t or n), n: col
        Ct[r * PADT + n] = f2h(zx[(size_t)(m0 + r) * NPROJ + OFF_C + n]);
        // H: read [n=r][d=n-col] coalesced, store transposed [d][n]
        Hdn[n * PADT + r] = f2h(Hini[hbase + (size_t)r * HEAD_DIM + dq * 64 + n]);
    }
    __syncthreads();

    const int tm0 = wave * 16;
    f32x4 ya[4];
#pragma unroll
    for (int j = 0; j < 4; ++j) ya[j] = (f32x4)0.f;
#pragma unroll
    for (int kk = 0; kk < 2; ++kk) {
        f16x8 af = *(const f16x8*)&Ct[(tm0 + fr) * PADT + kk * 32 + quad * 8];
#pragma unroll
        for (int j = 0; j < 4; ++j) {
            f16x8 bf = *(const f16x8*)&Hdn[(j * 16 + fr) * PADT + kk * 32 + quad * 8];
            ya[j] = __builtin_amdgcn_mfma_f32_16x16x32_f16(af, bf, ya[j], 0, 0, 0);
        }
    }
#pragma unroll
    for (int reg = 0; reg < 4; ++reg) {
        int tt = tm0 + quad * 4 + reg;
        float cum = expf(Ahd * SDs[tt]);
#pragma unroll
        for (int j = 0; j < 4; ++j) {
            int dd = j * 16 + fr;
            size_t off = (size_t)(m0 + tt) * D_INNER + xcol + dd;
            yscan[off] += cum * ya[j][reg];
        }
    }
}

// ---------------------------------------------------------------------------
// y = (yscan + D*x) * silu(z); RMSNorm; emits single fp16. xh is fp16.
// ---------------------------------------------------------------------------
__global__ __launch_bounds__(256) void gate_norm_kernel(const float* __restrict__ zx,
                                                        const u16* __restrict__ xh,
                                                        const float* __restrict__ Dp,
                                                        const float* __restrict__ nw,
                                                        const float* __restrict__ y,
                                                        u16* __restrict__ ybf_h) {
    const int m = blockIdx.x;
    const int t = threadIdx.x;
    const size_t rowz = (size_t)m * NPROJ;
    const size_t rowy = (size_t)m * D_INNER;

    float v[8];
    float ss = 0.f;
#pragma unroll
    for (int i = 0; i < 8; ++i) {
        int c = t + i * 256;
        float ys = fmaf(Dp[c >> 8], h2f(xh[rowy + c]), y[rowy + c]);
        float z  = zx[rowz + OFF_Z + c];
        float gated = ys * (z / (1.f + expf(-z)));
        v[i] = gated;
        ss += gated * gated;
    }
#pragma unroll
    for (int off = 1; off < 64; off <<= 1) ss += __shfl_xor(ss, off);

    __shared__ float red[4];
    if ((t & 63) == 0) red[t >> 6] = ss;
    __syncthreads();
    float tot = red[0] + red[1] + red[2] + red[3];
    float scale = 1.f / sqrtf(tot / (float)D_INNER + 1e-6f);

#pragma unroll
    for (int i = 0; i < 8; ++i) {
        int c = t + i * 256;
        float o = v[i] * scale * nw[c];
        ybf_h[rowy + c] = f2h(o);
    }
}

// ---------------------------------------------------------------------------
extern "C" void kernel_launch(void* const* d_in, const int* in_sizes, int n_in,
                              void* d_out, int out_size, void* d_ws, size_t ws_size,
                              hipStream_t stream) {
    const float* x         = (const float*)d_in[0];
    const float* in_proj_w = (const float*)d_in[1];
    const float* conv_w    = (const float*)d_in[2];
    const float* conv_b    = (const float*)d_in[3];
    const float* A_log     = (const float*)d_in[4];
    const float* D_param   = (const float*)d_in[5];
    const float* dt_bias   = (const float*)d_in[6];
    const float* norm_w    = (const float*)d_in[7];
    const float* out_proj_w= (const float*)d_in[8];
    float* out = (float*)d_out;

    // workspace layout (floats), total 76.96 MB (unchanged):
    //  zx  @0         8,667,136  | later pbuf (2x 2,097,152 fits)
    //  R1  @8667136   2,166,784  | xh(u16) -> wobf_h(u16)
    //  R2  @10833920  4,194,304  | xbf_h -> ysc
    //  ab  @15028224     16,384
    //  R3  @15044608  4,194,304  | wibf_h -> Sloc -> ybf_h
    float* ws  = (float*)d_ws;
    float* zx  = ws;
    float* R1  = zx + 8667136;
    float* R2  = R1 + 2166784;
    float* ab  = R2 + 4194304;
    float* R3  = ab + 16384;

    u16*  xh     = (u16*)R1;
    u16*  wobf_h = (u16*)R1;                            // reuses xh after last read
    u16*  xbf_h  = (u16*)R2;
    float* ysc   = R2;
    u16*  wibf_h = (u16*)R3;
    float* Sloc  = R3;
    u16*  ybf_h  = (u16*)R3;
    float* pbuf  = zx;

    // 0) casts for GEMM1: x -> fp16, in_proj_w -> fp16
    {
        int n0 = M_ROWS * DIM;              // 2,097,152
        int n1 = NPROJ * DIM;               // 4,333,568
        cast2_kernel<<<(n0 + n1) / 1024, 256, 0, stream>>>(
            x, xbf_h, n0, in_proj_w, wibf_h, n1);
    }

    // 1) zxBCdt = x @ in_proj_w^T  (2048 x 4232, K=1024)
    gemm_mfma1<128><<<dim3(NPROJ_PAD / 128, M_ROWS / 128, 1), 256, 0, stream>>>(
        xbf_h, wibf_h, zx, DIM, NPROJ, NPROJ, NPROJ, 0);

    // 2) conv + silu -> xh (fp16) + dt/a_bar -> ab
    conv_silu_kernel<<<(M_ROWS * D_INNER) / 256, 256, 0, stream>>>(
        zx, conv_w, conv_b, dt_bias, A_log, xh, ab);

    // 3) SSD chunked scan (MFMA passes 1 and 3)
    scan_local_mfma<<<BATCH * N_HEADS * N_CHUNK * 4, 256, 0, stream>>>(
        zx, xh, dt_bias, A_log, ysc, Sloc);
    scan_combine_kernel<<<BATCH * N_HEADS * 16, 256, 0, stream>>>(ab, Sloc);
    scan_corr_mfma<<<BATCH * N_HEADS * N_CHUNK * 4, 256, 0, stream>>>(
        zx, dt_bias, A_log, Sloc, ysc);

    // 4) gate + rmsnorm, emits fp16 y
    gate_norm_kernel<<<M_ROWS, 256, 0, stream>>>(
        zx, xh, D_param, norm_w, ysc, ybf_h);

    // 5) fp16 cast for GEMM2 weights
    cast_h_kernel<<<(DIM * D_INNER) / 1024, 256, 0, stream>>>(
        out_proj_w, wobf_h, DIM * D_INNER);

    // 6) out = y @ out_proj_w^T  (2048 x 1024, K=2048), BN=64, split-K=2
    gemm_mfma1<64><<<dim3(DIM / 64, M_ROWS / 128, 2), 256, 0, stream>>>(
        ybf_h, wobf_h, pbuf, D_INNER, DIM, DIM, DIM,
        (size_t)M_ROWS * DIM);

    // 7) reduce partials -> out
    reduce2_kernel<<<(M_ROWS * DIM) / 1024, 256, 0, stream>>>(pbuf, out, M_ROWS * DIM);
}

// Round 4
// 205.043 us; speedup vs baseline: 1.3693x; 1.0964x over previous
//
#include <hip/hip_runtime.h>
#include <hip/hip_bf16.h>
#include <math.h>

#define DIM      1024
#define D_STATE  64
#define D_CONV   4
#define N_HEADS  8
#define D_INNER  2048
#define HEAD_DIM 256
#define NPROJ    4232      // 2048 + 2048 + 8 + 64 + 64
#define BATCH    2
#define SEQ      1024
#define M_ROWS   (BATCH * SEQ)   // 2048
#define OFF_Z    0
#define OFF_XC   2048
#define OFF_DT   4096
#define OFF_B    4104
#define OFF_C    4168

#define CHUNK    64
#define N_CHUNK  (SEQ / CHUNK)    // 16
#define STATE_PER_BH (HEAD_DIM * D_STATE)   // 16384 floats

#define NPROJ_PAD 4352            // 34 * 128 (GEMM1 grid only; B rows guarded)
#define PADT 72                   // padded u16 row pitch for 64-wide LDS tiles

typedef unsigned short u16;
typedef _Float16 f16x8 __attribute__((ext_vector_type(8)));
typedef float    f32x4 __attribute__((ext_vector_type(4)));

__device__ __forceinline__ u16 f2h(float f) {
    _Float16 h = (_Float16)f;
    return __builtin_bit_cast(u16, h);
}
__device__ __forceinline__ float h2f(u16 u) {
    return (float)__builtin_bit_cast(_Float16, u);
}

__device__ __forceinline__ void load_lds16(const void* g, void* l) {
    __builtin_amdgcn_global_load_lds((const __attribute__((address_space(1))) unsigned int*)g,
                                     (__attribute__((address_space(3))) unsigned int*)l,
                                     16, 0, 0);
}

__device__ __forceinline__ float softplus_f(float v) {
    return (v > 20.f) ? v : log1pf(expf(v));
}

// ---------------------------------------------------------------------------
// merged cast: x and in_proj_w -> single fp16 (fp16 input error ~2^-11 is
// far below the scan's fp16 noise floor; no hi/lo split needed).
// ---------------------------------------------------------------------------
__global__ __launch_bounds__(256) void cast2_kernel(
        const float* __restrict__ s0, u16* __restrict__ h0, int n0,
        const float* __restrict__ s1, u16* __restrict__ h1, int n1) {
    int i4 = (blockIdx.x * 256 + threadIdx.x) * 4;
    const float* src; u16* dst;
    if (i4 < n0) {
        src = s0; dst = h0;
    } else {
        i4 -= n0;
        if (i4 >= n1) return;
        src = s1; dst = h1;
    }
    float4 v = *(const float4*)&src[i4];
    ushort4 h;
    h.x = f2h(v.x); h.y = f2h(v.y); h.z = f2h(v.z); h.w = f2h(v.w);
    *(ushort4*)&dst[i4] = h;
}

// out_proj_w cast with norm_w folded in (diagonal commutes with row scaling)
__global__ __launch_bounds__(256) void cast_hn_kernel(const float* __restrict__ src,
                                                      const float* __restrict__ nw,
                                                      u16* __restrict__ hi, int n) {
    int i4 = (blockIdx.x * 256 + threadIdx.x) * 4;
    if (i4 >= n) return;
    float4 v = *(const float4*)&src[i4];
    int c = i4 & (D_INNER - 1);
    ushort4 h;
    h.x = f2h(v.x * nw[c]);
    h.y = f2h(v.y * nw[c + 1]);
    h.z = f2h(v.z * nw[c + 2]);
    h.w = f2h(v.w * nw[c + 3]);
    *(ushort4*)&hi[i4] = h;
}

// ---------------------------------------------------------------------------
// fp16 MFMA GEMM: C = A @ B^T, fp32 accum (m97 structure).
// BM=128 x BN tile, BK=32, 256 thr (2x2 waves).
// B rows guarded by NrowsB; stores by Nstore. Optional split-K via gridDim.z.
// ---------------------------------------------------------------------------
template<int BN>
__global__ __launch_bounds__(256) void gemm_mfma1(const u16* __restrict__ Ah,
                                                  const u16* __restrict__ Bh,
                                                  float* __restrict__ C,
                                                  int K, int ldc, int Nstore,
                                                  int NrowsB, size_t zstride) {
    __shared__ u16 As[128 * 32];
    __shared__ u16 Bs[BN * 32];

    const int tid  = threadIdx.x;
    const int wave = tid >> 6;
    const int lane = tid & 63;
    const int fr   = lane & 15;
    const int kc   = lane >> 4;
    const int m0   = blockIdx.y * 128;
    const int n0   = blockIdx.x * BN;
    const int wm   = (wave & 1) * 64;
    const int wn   = (wave >> 1) * (BN / 2);

    const int kPer = K / gridDim.z;
    const int kBeg = blockIdx.z * kPer;
    C += (size_t)blockIdx.z * zstride;

    f32x4 acc[4][BN / 32];
#pragma unroll
    for (int i = 0; i < 4; ++i)
#pragma unroll
        for (int j = 0; j < BN / 32; ++j) acc[i][j] = (f32x4)0.f;

    for (int k0 = kBeg; k0 < kBeg + kPer; k0 += 32) {
        __syncthreads();
#pragma unroll
        for (int q = 0; q < 2; ++q) {
            int s = wave * 128 + q * 64 + lane;
            int r = s >> 2, pc = s & 3;
            int gc = pc ^ ((r >> 1) & 3);
            size_t goff = (size_t)(m0 + r) * K + k0 + gc * 8;
            load_lds16(Ah + goff, &As[(wave * 128 + q * 64) * 8]);
        }
#pragma unroll
        for (int q = 0; q < BN / 64; ++q) {
            int s = wave * BN + q * 64 + lane;
            int r = s >> 2, pc = s & 3;
            int gc = pc ^ ((r >> 1) & 3);
            if (n0 + r < NrowsB) {   // OOB rows: stale LDS, results never stored
                size_t goff = (size_t)(n0 + r) * K + k0 + gc * 8;
                load_lds16(Bh + goff, &Bs[(wave * BN + q * 64) * 8]);
            }
        }
        __syncthreads();

        f16x8 af[4];
#pragma unroll
        for (int i = 0; i < 4; ++i) {
            int r = wm + i * 16 + fr;
            int off = r * 32 + (kc ^ ((r >> 1) & 3)) * 8;
            af[i] = *(const f16x8*)&As[off];
        }
        f16x8 bf[BN / 32];
#pragma unroll
        for (int j = 0; j < BN / 32; ++j) {
            int r = wn + j * 16 + fr;
            int off = r * 32 + (kc ^ ((r >> 1) & 3)) * 8;
            bf[j] = *(const f16x8*)&Bs[off];
        }
#pragma unroll
        for (int i = 0; i < 4; ++i)
#pragma unroll
            for (int j = 0; j < BN / 32; ++j)
                acc[i][j] = __builtin_amdgcn_mfma_f32_16x16x32_f16(af[i], bf[j], acc[i][j], 0, 0, 0);
    }

    // epilogue: C/D layout col=lane&15, row=(lane>>4)*4+reg  [m89/m91]
    const int row0 = m0 + wm + (lane >> 4) * 4;
    const int colb = n0 + wn + fr;
#pragma unroll
    for (int i = 0; i < 4; ++i)
#pragma unroll
        for (int j = 0; j < BN / 32; ++j) {
            int col = colb + j * 16;
            if (col < Nstore) {
#pragma unroll
                for (int t = 0; t < 4; ++t)
                    C[(size_t)(row0 + i * 16 + t) * ldc + col] = acc[i][j][t];
            }
        }
}

// ---------------------------------------------------------------------------
// split-K=2 reduce + per-row RMS scale (rowSS = sum of squares of gated y)
// ---------------------------------------------------------------------------
__global__ __launch_bounds__(256) void reduce2rms_kernel(const float* __restrict__ p,
                                                         const float* __restrict__ rowSS,
                                                         float* __restrict__ out, int n) {
    int i4 = (blockIdx.x * 256 + threadIdx.x) * 4;
    int m = i4 >> 10;                         // DIM=1024 cols per row
    float scale = rsqrtf(rowSS[m] * (1.f / (float)D_INNER) + 1e-6f);
    float4 a = *(const float4*)&p[i4];
    float4 b = *(const float4*)&p[(size_t)n + i4];
    *(float4*)&out[i4] = make_float4((a.x + b.x) * scale, (a.y + b.y) * scale,
                                     (a.z + b.z) * scale, (a.w + b.w) * scale);
}

// ---------------------------------------------------------------------------
// depthwise causal conv (k=4) + SiLU -> xh (fp16)
// ---------------------------------------------------------------------------
__global__ __launch_bounds__(256) void conv_silu_kernel(const float* __restrict__ zx,
                                                        const float* __restrict__ conv_w,
                                                        const float* __restrict__ conv_b,
                                                        u16* __restrict__ xh) {
    int idx = blockIdx.x * 256 + threadIdx.x;
    int c = idx & (D_INNER - 1);
    int m = idx >> 11;
    int l = m & (SEQ - 1);
    float acc = conv_b[c];
#pragma unroll
    for (int k = 0; k < D_CONV; ++k) {
        int lj = l + k - (D_CONV - 1);
        if (lj >= 0)
            acc = fmaf(zx[(size_t)(m + k - (D_CONV - 1)) * NPROJ + OFF_XC + c],
                       conv_w[c * D_CONV + k], acc);
    }
    xh[idx] = f2h(acc / (1.f + expf(-acc)));
}

// ---------------------------------------------------------------------------
// PASS 1 (states only): per (b,h,chunk,dq): S_c = (w2*B)^T @ X  -> Sloc.
// dq==0 block also writes csum[bh][c] = sum of dt over the chunk (SD63).
// ---------------------------------------------------------------------------
__global__ __launch_bounds__(256) void scan_state_mfma(const float* __restrict__ zx,
                                                       const u16* __restrict__ xh,
                                                       const float* __restrict__ dt_bias,
                                                       const float* __restrict__ A_log,
                                                       float* __restrict__ Sloc,
                                                       float* __restrict__ csum) {
    const int blk = blockIdx.x;                 // 0..1023
    const int dq = blk & 3;
    const int c  = (blk >> 2) & (N_CHUNK - 1);
    const int bh = blk >> 6;
    const int hh = bh & (N_HEADS - 1);
    const int b  = bh >> 3;
    const int t    = threadIdx.x;
    const int wave = t >> 6;
    const int lane = t & 63;
    const int fr   = lane & 15;
    const int quad = lane >> 4;

    __shared__ float SDs[64];
    __shared__ u16 BwT[64 * PADT];
    __shared__ u16 XsT[64 * PADT];

    const int m0   = b * SEQ + c * CHUNK;
    const int xcol = hh * HEAD_DIM + dq * 64;
    const float Ahd = -expf(A_log[hh]);
    const float dtb = dt_bias[hh];

    if (t < 64) {
        float d = softplus_f(zx[(size_t)(m0 + t) * NPROJ + OFF_DT + hh] + dtb);
#pragma unroll
        for (int off = 1; off < 64; off <<= 1) {
            float o = __shfl_up(d, off);
            if (lane >= off) d += o;
        }
        SDs[t] = d;
    }
    __syncthreads();
    const float SD63 = SDs[63];
    if (dq == 0 && t == 0) csum[bh * N_CHUNK + c] = SD63;

#pragma unroll
    for (int i = 0; i < 16; ++i) {
        int idx = t + i * 256;
        int r = idx >> 6, n = idx & 63;
        float bv = zx[(size_t)(m0 + r) * NPROJ + OFF_B + n];
        float w2 = expf(Ahd * (SD63 - SDs[r]));
        BwT[n * PADT + r] = f2h(bv * w2);
        XsT[n * PADT + r] = xh[(size_t)(m0 + r) * D_INNER + xcol + n];
    }
    __syncthreads();

    const int tm0 = wave * 16;
    f32x4 sa[4];
#pragma unroll
    for (int j = 0; j < 4; ++j) sa[j] = (f32x4)0.f;
#pragma unroll
    for (int kk = 0; kk < 2; ++kk) {
        f16x8 af = *(const f16x8*)&BwT[(tm0 + fr) * PADT + kk * 32 + quad * 8];
#pragma unroll
        for (int j = 0; j < 4; ++j) {
            f16x8 bf = *(const f16x8*)&XsT[(j * 16 + fr) * PADT + kk * 32 + quad * 8];
            sa[j] = __builtin_amdgcn_mfma_f32_16x16x32_f16(af, bf, sa[j], 0, 0, 0);
        }
    }
    size_t sbase = (size_t)(bh * N_CHUNK + c) * STATE_PER_BH;
#pragma unroll
    for (int j = 0; j < 4; ++j)
#pragma unroll
        for (int reg = 0; reg < 4; ++reg) {
            int nn = tm0 + quad * 4 + reg;
            int dd = j * 16 + fr;
            Sloc[sbase + (size_t)nn * HEAD_DIM + dq * 64 + dd] = sa[j][reg];
        }
}

// ---------------------------------------------------------------------------
// PASS 2: inter-chunk recurrence in place on Sloc -> H_init(c).
// PS[c] = exp(Ahd * csum[c]); all 16 chunk loads issued up-front.
// ---------------------------------------------------------------------------
__global__ __launch_bounds__(256) void scan_combine2(const float* __restrict__ csum,
                                                     const float* __restrict__ A_log,
                                                     float* __restrict__ Sloc) {
    const int blk = blockIdx.x;               // 0..1023
    const int seg = blk & 63;
    const int bh  = blk >> 6;
    const int hh  = bh & (N_HEADS - 1);
    const int t   = threadIdx.x;

    __shared__ float PS[N_CHUNK];
    if (t < N_CHUNK) {
        float Ahd = -expf(A_log[hh]);
        PS[t] = expf(Ahd * csum[bh * N_CHUNK + t]);
    }
    __syncthreads();

    size_t base = (size_t)bh * N_CHUNK * STATE_PER_BH + seg * 256 + t;
    float Sv[N_CHUNK];
#pragma unroll
    for (int c = 0; c < N_CHUNK; ++c)
        Sv[c] = Sloc[base + (size_t)c * STATE_PER_BH];
    float H = 0.f;
#pragma unroll
    for (int c = 0; c < N_CHUNK; ++c) {
        Sloc[base + (size_t)c * STATE_PER_BH] = H;
        H = fmaf(PS[c], H, Sv[c]);
    }
}

// ---------------------------------------------------------------------------
// PASS 3 (fused): per (b,h,chunk,dq):
//   G = C@B^T; P = mask*decay*G; Y = P@X + cum*(C@H) + D*x;
//   ybf = fp16((Y) * silu(z)); rowSS += per-row sum of squares.
// ---------------------------------------------------------------------------
__global__ __launch_bounds__(256) void scan_ycorr_mfma(const float* __restrict__ zx,
                                                       const u16* __restrict__ xh,
                                                       const float* __restrict__ dt_bias,
                                                       const float* __restrict__ A_log,
                                                       const float* __restrict__ Dp,
                                                       const float* __restrict__ Hini,
                                                       u16* __restrict__ ybf,
                                                       float* __restrict__ rowSS) {
    const int blk = blockIdx.x;                 // 0..1023
    const int dq = blk & 3;
    const int c  = (blk >> 2) & (N_CHUNK - 1);
    const int bh = blk >> 6;
    const int hh = bh & (N_HEADS - 1);
    const int b  = bh >> 3;
    const int t    = threadIdx.x;
    const int wave = t >> 6;
    const int lane = t & 63;
    const int fr   = lane & 15;
    const int quad = lane >> 4;

    __shared__ float SDs[64];
    __shared__ u16 Ct [64 * PADT];
    __shared__ u16 Bt [64 * PADT];
    __shared__ u16 Ps [64 * PADT];
    __shared__ u16 XsT[64 * PADT];
    __shared__ u16 Hdn[64 * PADT];

    const int m0   = b * SEQ + c * CHUNK;
    const int xcol = hh * HEAD_DIM + dq * 64;
    const float Ahd = -expf(A_log[hh]);
    const float dtb = dt_bias[hh];

    if (t < 64) {
        float d = softplus_f(zx[(size_t)(m0 + t) * NPROJ + OFF_DT + hh] + dtb);
#pragma unroll
        for (int off = 1; off < 64; off <<= 1) {
            float o = __shfl_up(d, off);
            if (lane >= off) d += o;
        }
        SDs[t] = d;
    }
    __syncthreads();

    size_t hbase = (size_t)(bh * N_CHUNK + c) * STATE_PER_BH;
#pragma unroll
    for (int i = 0; i < 16; ++i) {
        int idx = t + i * 256;
        int r = idx >> 6, n = idx & 63;
        size_t rowz = (size_t)(m0 + r) * NPROJ;
        Bt[r * PADT + n] = f2h(zx[rowz + OFF_B + n]);
        Ct[r * PADT + n] = f2h(zx[rowz + OFF_C + n]);
        XsT[n * PADT + r] = xh[(size_t)(m0 + r) * D_INNER + xcol + n];
        Hdn[n * PADT + r] = f2h(Hini[hbase + (size_t)r * HEAD_DIM + dq * 64 + n]);
    }
    __syncthreads();

    const int tm0 = wave * 16;

    // G = C@B^T
    f32x4 g[4];
#pragma unroll
    for (int j = 0; j < 4; ++j) g[j] = (f32x4)0.f;
#pragma unroll
    for (int kk = 0; kk < 2; ++kk) {
        f16x8 af = *(const f16x8*)&Ct[(tm0 + fr) * PADT + kk * 32 + quad * 8];
#pragma unroll
        for (int j = 0; j < 4; ++j) {
            f16x8 bf = *(const f16x8*)&Bt[(j * 16 + fr) * PADT + kk * 32 + quad * 8];
            g[j] = __builtin_amdgcn_mfma_f32_16x16x32_f16(af, bf, g[j], 0, 0, 0);
        }
    }
    // mask + decay -> Ps (same-wave rows only; no barrier needed)
    {
        int trow = tm0 + quad * 4;
#pragma unroll
        for (int j = 0; j < 4; ++j) {
#pragma unroll
            for (int reg = 0; reg < 4; ++reg) {
                int tt = trow + reg, ss = j * 16 + fr;
                float val = 0.f;
                if (ss <= tt) val = expf(Ahd * (SDs[tt] - SDs[ss])) * g[j][reg];
                Ps[tt * PADT + ss] = f2h(val);
            }
        }
    }

    // Y1 = P @ X ; Y2 = C @ H
    f32x4 ya[4], yb[4];
#pragma unroll
    for (int j = 0; j < 4; ++j) { ya[j] = (f32x4)0.f; yb[j] = (f32x4)0.f; }
#pragma unroll
    for (int kk = 0; kk < 2; ++kk) {
        f16x8 afp = *(const f16x8*)&Ps[(tm0 + fr) * PADT + kk * 32 + quad * 8];
        f16x8 afc = *(const f16x8*)&Ct[(tm0 + fr) * PADT + kk * 32 + quad * 8];
#pragma unroll
        for (int j = 0; j < 4; ++j) {
            f16x8 bx = *(const f16x8*)&XsT[(j * 16 + fr) * PADT + kk * 32 + quad * 8];
            f16x8 bh_ = *(const f16x8*)&Hdn[(j * 16 + fr) * PADT + kk * 32 + quad * 8];
            ya[j] = __builtin_amdgcn_mfma_f32_16x16x32_f16(afp, bx, ya[j], 0, 0, 0);
            yb[j] = __builtin_amdgcn_mfma_f32_16x16x32_f16(afc, bh_, yb[j], 0, 0, 0);
        }
    }

    // epilogue: gate + fp16 store + row sum-of-squares
    const float Dh = Dp[hh];
#pragma unroll
    for (int reg = 0; reg < 4; ++reg) {
        int tt = tm0 + quad * 4 + reg;
        float cum = expf(Ahd * SDs[tt]);
        size_t rowz = (size_t)(m0 + tt) * NPROJ;
        size_t rowy = (size_t)(m0 + tt) * D_INNER + xcol;
        float ss = 0.f;
#pragma unroll
        for (int j = 0; j < 4; ++j) {
            int dd = j * 16 + fr;
            float xv = h2f(XsT[dd * PADT + tt]);
            float z  = zx[rowz + OFF_Z + xcol + dd];
            float yv = ya[j][reg] + cum * yb[j][reg] + Dh * xv;
            float gated = yv * (z / (1.f + expf(-z)));
            ybf[rowy + dd] = f2h(gated);
            ss += gated * gated;
        }
        // reduce across the 16 lanes of this quad (fr dimension)
#pragma unroll
        for (int off = 1; off < 16; off <<= 1) ss += __shfl_xor(ss, off);
        if (fr == 0) atomicAdd(&rowSS[m0 + tt], ss);
    }
}

// ---------------------------------------------------------------------------
extern "C" void kernel_launch(void* const* d_in, const int* in_sizes, int n_in,
                              void* d_out, int out_size, void* d_ws, size_t ws_size,
                              hipStream_t stream) {
    const float* x         = (const float*)d_in[0];
    const float* in_proj_w = (const float*)d_in[1];
    const float* conv_w    = (const float*)d_in[2];
    const float* conv_b    = (const float*)d_in[3];
    const float* A_log     = (const float*)d_in[4];
    const float* D_param   = (const float*)d_in[5];
    const float* dt_bias   = (const float*)d_in[6];
    const float* norm_w    = (const float*)d_in[7];
    const float* out_proj_w= (const float*)d_in[8];
    float* out = (float*)d_out;

    // workspace layout (floats), total 76.96 MB:
    //  zx  @0         8,667,136  | later pbuf (2x 2,097,152 fits)
    //  R1  @8667136   2,166,784  | xh(u16) -> wobf_h(u16)
    //  R2  @10833920  4,194,304  | xbf_h(u16) -> ybf(u16)
    //  ab  @15028224     16,384  | csum(256) + rowSS(2048)
    //  R3  @15044608  4,194,304  | wibf_h(u16) -> Sloc(fp32)
    float* ws  = (float*)d_ws;
    float* zx  = ws;
    float* R1  = zx + 8667136;
    float* R2  = R1 + 2166784;
    float* ab  = R2 + 4194304;
    float* R3  = ab + 16384;

    u16*  xh     = (u16*)R1;
    u16*  wobf_h = (u16*)R1;     // reuses xh region after last xh read
    u16*  xbf_h  = (u16*)R2;
    u16*  ybf    = (u16*)R2;     // reuses xbf region after GEMM1
    float* csum  = ab;
    float* rowSS = ab + 2048;
    u16*  wibf_h = (u16*)R3;
    float* Sloc  = R3;
    float* pbuf  = zx;

    // 0) zero rowSS (8 KB) + casts for GEMM1
    hipMemsetAsync(rowSS, 0, M_ROWS * sizeof(float), stream);
    {
        int n0 = M_ROWS * DIM;              // 2,097,152
        int n1 = NPROJ * DIM;               // 4,333,568
        cast2_kernel<<<(n0 + n1) / 1024, 256, 0, stream>>>(
            x, xbf_h, n0, in_proj_w, wibf_h, n1);
    }

    // 1) zxBCdt = x @ in_proj_w^T  (2048 x 4232, K=1024)
    gemm_mfma1<128><<<dim3(NPROJ_PAD / 128, M_ROWS / 128, 1), 256, 0, stream>>>(
        xbf_h, wibf_h, zx, DIM, NPROJ, NPROJ, NPROJ, 0);

    // 2) conv + silu -> xh (fp16)
    conv_silu_kernel<<<(M_ROWS * D_INNER) / 256, 256, 0, stream>>>(
        zx, conv_w, conv_b, xh);

    // 3) SSD chunked scan
    scan_state_mfma<<<BATCH * N_HEADS * N_CHUNK * 4, 256, 0, stream>>>(
        zx, xh, dt_bias, A_log, Sloc, csum);
    scan_combine2<<<BATCH * N_HEADS * 64, 256, 0, stream>>>(csum, A_log, Sloc);
    scan_ycorr_mfma<<<BATCH * N_HEADS * N_CHUNK * 4, 256, 0, stream>>>(
        zx, xh, dt_bias, A_log, D_param, Sloc, ybf, rowSS);

    // 4) fp16 cast for GEMM2 weights, norm_w folded in
    cast_hn_kernel<<<(DIM * D_INNER) / 1024, 256, 0, stream>>>(
        out_proj_w, norm_w, wobf_h, DIM * D_INNER);

    // 5) out_pre = y_gated @ (W*nw)^T  (2048 x 1024, K=2048), BN=64, split-K=2
    gemm_mfma1<64><<<dim3(DIM / 64, M_ROWS / 128, 2), 256, 0, stream>>>(
        ybf, wobf_h, pbuf, D_INNER, DIM, DIM, DIM,
        (size_t)M_ROWS * DIM);

    // 6) reduce partials + apply per-row RMS scale -> out
    reduce2rms_kernel<<<(M_ROWS * DIM) / 1024, 256, 0, stream>>>(
        pbuf, rowSS, out, M_ROWS * DIM);
}

// Round 5
// 203.206 us; speedup vs baseline: 1.3817x; 1.0090x over previous
//
#include <hip/hip_runtime.h>
#include <hip/hip_bf16.h>
#include <math.h>

#define DIM      1024
#define D_STATE  64
#define D_CONV   4
#define N_HEADS  8
#define D_INNER  2048
#define HEAD_DIM 256
#define NPROJ    4232      // 2048 + 2048 + 8 + 64 + 64
#define BATCH    2
#define SEQ      1024
#define M_ROWS   (BATCH * SEQ)   // 2048
#define OFF_Z    0
#define OFF_XC   2048
#define OFF_DT   4096
#define OFF_B    4104
#define OFF_C    4168

#define CHUNK    64
#define N_CHUNK  (SEQ / CHUNK)    // 16
#define STATE_PER_BH (HEAD_DIM * D_STATE)   // 16384 elems

#define NPROJ_PAD 4352            // 34 * 128 (GEMM1 grid only; B rows guarded)
#define PADT 72                   // padded u16 row pitch for 64-wide LDS tiles

typedef unsigned short u16;
typedef unsigned int   u32;
typedef _Float16 f16x8 __attribute__((ext_vector_type(8)));
typedef float    f32x4 __attribute__((ext_vector_type(4)));

__device__ __forceinline__ u16 f2h(float f) {
    _Float16 h = (_Float16)f;
    return __builtin_bit_cast(u16, h);
}
__device__ __forceinline__ float h2f(u16 u) {
    return (float)__builtin_bit_cast(_Float16, u);
}

__device__ __forceinline__ void load_lds16(const void* g, void* l) {
    __builtin_amdgcn_global_load_lds((const __attribute__((address_space(1))) unsigned int*)g,
                                     (__attribute__((address_space(3))) unsigned int*)l,
                                     16, 0, 0);
}

__device__ __forceinline__ float softplus_f(float v) {
    return (v > 20.f) ? v : log1pf(expf(v));
}

// ---------------------------------------------------------------------------
// merged cast: x and in_proj_w -> single fp16.
// ---------------------------------------------------------------------------
__global__ __launch_bounds__(256) void cast2_kernel(
        const float* __restrict__ s0, u16* __restrict__ h0, int n0,
        const float* __restrict__ s1, u16* __restrict__ h1, int n1) {
    int i4 = (blockIdx.x * 256 + threadIdx.x) * 4;
    const float* src; u16* dst;
    if (i4 < n0) {
        src = s0; dst = h0;
    } else {
        i4 -= n0;
        if (i4 >= n1) return;
        src = s1; dst = h1;
    }
    float4 v = *(const float4*)&src[i4];
    ushort4 h;
    h.x = f2h(v.x); h.y = f2h(v.y); h.z = f2h(v.z); h.w = f2h(v.w);
    *(ushort4*)&dst[i4] = h;
}

// out_proj_w cast with norm_w folded in (diagonal commutes with row scaling)
__global__ __launch_bounds__(256) void cast_hn_kernel(const float* __restrict__ src,
                                                      const float* __restrict__ nw,
                                                      u16* __restrict__ hi, int n) {
    int i4 = (blockIdx.x * 256 + threadIdx.x) * 4;
    if (i4 >= n) return;
    float4 v = *(const float4*)&src[i4];
    int c = i4 & (D_INNER - 1);
    ushort4 h;
    h.x = f2h(v.x * nw[c]);
    h.y = f2h(v.y * nw[c + 1]);
    h.z = f2h(v.z * nw[c + 2]);
    h.w = f2h(v.w * nw[c + 3]);
    *(ushort4*)&hi[i4] = h;
}

// ---------------------------------------------------------------------------
// fp16 MFMA GEMM: C = A @ B^T, fp32 accum (m97 structure).
// BM=128 x BN tile, BK=32, 256 thr (2x2 waves).
// ---------------------------------------------------------------------------
template<int BN>
__global__ __launch_bounds__(256) void gemm_mfma1(const u16* __restrict__ Ah,
                                                  const u16* __restrict__ Bh,
                                                  float* __restrict__ C,
                                                  int K, int ldc, int Nstore,
                                                  int NrowsB, size_t zstride) {
    __shared__ u16 As[128 * 32];
    __shared__ u16 Bs[BN * 32];

    const int tid  = threadIdx.x;
    const int wave = tid >> 6;
    const int lane = tid & 63;
    const int fr   = lane & 15;
    const int kc   = lane >> 4;
    const int m0   = blockIdx.y * 128;
    const int n0   = blockIdx.x * BN;
    const int wm   = (wave & 1) * 64;
    const int wn   = (wave >> 1) * (BN / 2);

    const int kPer = K / gridDim.z;
    const int kBeg = blockIdx.z * kPer;
    C += (size_t)blockIdx.z * zstride;

    f32x4 acc[4][BN / 32];
#pragma unroll
    for (int i = 0; i < 4; ++i)
#pragma unroll
        for (int j = 0; j < BN / 32; ++j) acc[i][j] = (f32x4)0.f;

    for (int k0 = kBeg; k0 < kBeg + kPer; k0 += 32) {
        __syncthreads();
#pragma unroll
        for (int q = 0; q < 2; ++q) {
            int s = wave * 128 + q * 64 + lane;
            int r = s >> 2, pc = s & 3;
            int gc = pc ^ ((r >> 1) & 3);
            size_t goff = (size_t)(m0 + r) * K + k0 + gc * 8;
            load_lds16(Ah + goff, &As[(wave * 128 + q * 64) * 8]);
        }
#pragma unroll
        for (int q = 0; q < BN / 64; ++q) {
            int s = wave * BN + q * 64 + lane;
            int r = s >> 2, pc = s & 3;
            int gc = pc ^ ((r >> 1) & 3);
            if (n0 + r < NrowsB) {   // OOB rows: stale LDS, results never stored
                size_t goff = (size_t)(n0 + r) * K + k0 + gc * 8;
                load_lds16(Bh + goff, &Bs[(wave * BN + q * 64) * 8]);
            }
        }
        __syncthreads();

        f16x8 af[4];
#pragma unroll
        for (int i = 0; i < 4; ++i) {
            int r = wm + i * 16 + fr;
            int off = r * 32 + (kc ^ ((r >> 1) & 3)) * 8;
            af[i] = *(const f16x8*)&As[off];
        }
        f16x8 bf[BN / 32];
#pragma unroll
        for (int j = 0; j < BN / 32; ++j) {
            int r = wn + j * 16 + fr;
            int off = r * 32 + (kc ^ ((r >> 1) & 3)) * 8;
            bf[j] = *(const f16x8*)&Bs[off];
        }
#pragma unroll
        for (int i = 0; i < 4; ++i)
#pragma unroll
            for (int j = 0; j < BN / 32; ++j)
                acc[i][j] = __builtin_amdgcn_mfma_f32_16x16x32_f16(af[i], bf[j], acc[i][j], 0, 0, 0);
    }

    // epilogue: C/D layout col=lane&15, row=(lane>>4)*4+reg  [m89/m91]
    const int row0 = m0 + wm + (lane >> 4) * 4;
    const int colb = n0 + wn + fr;
#pragma unroll
    for (int i = 0; i < 4; ++i)
#pragma unroll
        for (int j = 0; j < BN / 32; ++j) {
            int col = colb + j * 16;
            if (col < Nstore) {
#pragma unroll
                for (int t = 0; t < 4; ++t)
                    C[(size_t)(row0 + i * 16 + t) * ldc + col] = acc[i][j][t];
            }
        }
}

// ---------------------------------------------------------------------------
// split-K=2 reduce + per-row RMS scale (rowSS = sum of squares of gated y)
// ---------------------------------------------------------------------------
__global__ __launch_bounds__(256) void reduce2rms_kernel(const float* __restrict__ p,
                                                         const float* __restrict__ rowSS,
                                                         float* __restrict__ out, int n) {
    int i4 = (blockIdx.x * 256 + threadIdx.x) * 4;
    int m = i4 >> 10;                         // DIM=1024 cols per row
    float scale = rsqrtf(rowSS[m] * (1.f / (float)D_INNER) + 1e-6f);
    float4 a = *(const float4*)&p[i4];
    float4 b = *(const float4*)&p[(size_t)n + i4];
    *(float4*)&out[i4] = make_float4((a.x + b.x) * scale, (a.y + b.y) * scale,
                                     (a.z + b.z) * scale, (a.w + b.w) * scale);
}

// ---------------------------------------------------------------------------
// depthwise causal conv (k=4) + SiLU -> xh (fp16)
// ---------------------------------------------------------------------------
__global__ __launch_bounds__(256) void conv_silu_kernel(const float* __restrict__ zx,
                                                        const float* __restrict__ conv_w,
                                                        const float* __restrict__ conv_b,
                                                        u16* __restrict__ xh) {
    int idx = blockIdx.x * 256 + threadIdx.x;
    int c = idx & (D_INNER - 1);
    int m = idx >> 11;
    int l = m & (SEQ - 1);
    float acc = conv_b[c];
#pragma unroll
    for (int k = 0; k < D_CONV; ++k) {
        int lj = l + k - (D_CONV - 1);
        if (lj >= 0)
            acc = fmaf(zx[(size_t)(m + k - (D_CONV - 1)) * NPROJ + OFF_XC + c],
                       conv_w[c * D_CONV + k], acc);
    }
    xh[idx] = f2h(acc / (1.f + expf(-acc)));
}

// ---------------------------------------------------------------------------
// PASS 1 (states only): per (b,h,chunk,dq): S_c = (w2*B)^T @ X  -> Sloc (fp16).
// dq==0 block also writes csum[bh][c] = sum of dt over the chunk (SD63).
// ---------------------------------------------------------------------------
__global__ __launch_bounds__(256) void scan_state_mfma(const float* __restrict__ zx,
                                                       const u16* __restrict__ xh,
                                                       const float* __restrict__ dt_bias,
                                                       const float* __restrict__ A_log,
                                                       u16* __restrict__ Sloc,
                                                       float* __restrict__ csum) {
    const int blk = blockIdx.x;                 // 0..1023
    const int dq = blk & 3;
    const int c  = (blk >> 2) & (N_CHUNK - 1);
    const int bh = blk >> 6;
    const int hh = bh & (N_HEADS - 1);
    const int b  = bh >> 3;
    const int t    = threadIdx.x;
    const int wave = t >> 6;
    const int lane = t & 63;
    const int fr   = lane & 15;
    const int quad = lane >> 4;

    __shared__ float SDs[64];
    __shared__ u16 BwT[64 * PADT];
    __shared__ u16 XsT[64 * PADT];

    const int m0   = b * SEQ + c * CHUNK;
    const int xcol = hh * HEAD_DIM + dq * 64;
    const float Ahd = -expf(A_log[hh]);
    const float dtb = dt_bias[hh];

    if (t < 64) {
        float d = softplus_f(zx[(size_t)(m0 + t) * NPROJ + OFF_DT + hh] + dtb);
#pragma unroll
        for (int off = 1; off < 64; off <<= 1) {
            float o = __shfl_up(d, off);
            if (lane >= off) d += o;
        }
        SDs[t] = d;
    }
    __syncthreads();
    const float SD63 = SDs[63];
    if (dq == 0 && t == 0) csum[bh * N_CHUNK + c] = SD63;

#pragma unroll
    for (int i = 0; i < 16; ++i) {
        int idx = t + i * 256;
        int r = idx >> 6, n = idx & 63;
        float bv = zx[(size_t)(m0 + r) * NPROJ + OFF_B + n];
        float w2 = expf(Ahd * (SD63 - SDs[r]));
        BwT[n * PADT + r] = f2h(bv * w2);
        XsT[n * PADT + r] = xh[(size_t)(m0 + r) * D_INNER + xcol + n];
    }
    __syncthreads();

    const int tm0 = wave * 16;
    f32x4 sa[4];
#pragma unroll
    for (int j = 0; j < 4; ++j) sa[j] = (f32x4)0.f;
#pragma unroll
    for (int kk = 0; kk < 2; ++kk) {
        f16x8 af = *(const f16x8*)&BwT[(tm0 + fr) * PADT + kk * 32 + quad * 8];
#pragma unroll
        for (int j = 0; j < 4; ++j) {
            f16x8 bf = *(const f16x8*)&XsT[(j * 16 + fr) * PADT + kk * 32 + quad * 8];
            sa[j] = __builtin_amdgcn_mfma_f32_16x16x32_f16(af, bf, sa[j], 0, 0, 0);
        }
    }
    size_t sbase = (size_t)(bh * N_CHUNK + c) * STATE_PER_BH;
#pragma unroll
    for (int j = 0; j < 4; ++j)
#pragma unroll
        for (int reg = 0; reg < 4; ++reg) {
            int nn = tm0 + quad * 4 + reg;
            int dd = j * 16 + fr;
            Sloc[sbase + (size_t)nn * HEAD_DIM + dq * 64 + dd] = f2h(sa[j][reg]);
        }
}

// ---------------------------------------------------------------------------
// PASS 2: inter-chunk recurrence in place on fp16 Sloc (u32 = 2 packed fp16).
// PS[c] = exp(Ahd * csum[c]); recurrence kept in fp32 registers.
// ---------------------------------------------------------------------------
__global__ __launch_bounds__(256) void scan_combine2(const float* __restrict__ csum,
                                                     const float* __restrict__ A_log,
                                                     u32* __restrict__ Sl) {
    const int blk = blockIdx.x;               // 0..511
    const int seg = blk & 31;                 // 32 segs x 256 u32 = 8192 u32/chunk
    const int bh  = blk >> 5;
    const int hh  = bh & (N_HEADS - 1);
    const int t   = threadIdx.x;

    __shared__ float PS[N_CHUNK];
    if (t < N_CHUNK) {
        float Ahd = -expf(A_log[hh]);
        PS[t] = expf(Ahd * csum[bh * N_CHUNK + t]);
    }
    __syncthreads();

    const int HPC = STATE_PER_BH / 2;         // 8192 u32 per chunk
    size_t base = (size_t)bh * N_CHUNK * HPC + seg * 256 + t;
    u32 Sv[N_CHUNK];
#pragma unroll
    for (int c = 0; c < N_CHUNK; ++c)
        Sv[c] = Sl[base + (size_t)c * HPC];
    float H0 = 0.f, H1 = 0.f;
#pragma unroll
    for (int c = 0; c < N_CHUNK; ++c) {
        Sl[base + (size_t)c * HPC] = ((u32)f2h(H1) << 16) | (u32)f2h(H0);
        float P = PS[c];
        H0 = fmaf(P, H0, h2f((u16)(Sv[c] & 0xffffu)));
        H1 = fmaf(P, H1, h2f((u16)(Sv[c] >> 16)));
    }
}

// ---------------------------------------------------------------------------
// PASS 3 (fused): per (b,h,chunk,dq):
//   G = C@B^T; P = mask*decay*G; Y = P@X + cum*(C@H) + D*x;
//   ybf = fp16(Y * silu(z)); rowSS += per-row sum of squares.
// ---------------------------------------------------------------------------
__global__ __launch_bounds__(256) void scan_ycorr_mfma(const float* __restrict__ zx,
                                                       const u16* __restrict__ xh,
                                                       const float* __restrict__ dt_bias,
                                                       const float* __restrict__ A_log,
                                                       const float* __restrict__ Dp,
                                                       const u16* __restrict__ Hini,
                                                       u16* __restrict__ ybf,
                                                       float* __restrict__ rowSS) {
    const int blk = blockIdx.x;                 // 0..1023
    const int dq = blk & 3;
    const int c  = (blk >> 2) & (N_CHUNK - 1);
    const int bh = blk >> 6;
    const int hh = bh & (N_HEADS - 1);
    const int b  = bh >> 3;
    const int t    = threadIdx.x;
    const int wave = t >> 6;
    const int lane = t & 63;
    const int fr   = lane & 15;
    const int quad = lane >> 4;

    __shared__ float SDs[64];
    __shared__ u16 Ct [64 * PADT];
    __shared__ u16 Bt [64 * PADT];
    __shared__ u16 Ps [64 * PADT];
    __shared__ u16 XsT[64 * PADT];
    __shared__ u16 Hdn[64 * PADT];

    const int m0   = b * SEQ + c * CHUNK;
    const int xcol = hh * HEAD_DIM + dq * 64;
    const float Ahd = -expf(A_log[hh]);
    const float dtb = dt_bias[hh];

    if (t < 64) {
        float d = softplus_f(zx[(size_t)(m0 + t) * NPROJ + OFF_DT + hh] + dtb);
#pragma unroll
        for (int off = 1; off < 64; off <<= 1) {
            float o = __shfl_up(d, off);
            if (lane >= off) d += o;
        }
        SDs[t] = d;
    }
    __syncthreads();

    size_t hbase = (size_t)(bh * N_CHUNK + c) * STATE_PER_BH;
#pragma unroll
    for (int i = 0; i < 16; ++i) {
        int idx = t + i * 256;
        int r = idx >> 6, n = idx & 63;
        size_t rowz = (size_t)(m0 + r) * NPROJ;
        Bt[r * PADT + n] = f2h(zx[rowz + OFF_B + n]);
        Ct[r * PADT + n] = f2h(zx[rowz + OFF_C + n]);
        XsT[n * PADT + r] = xh[(size_t)(m0 + r) * D_INNER + xcol + n];
        Hdn[n * PADT + r] = Hini[hbase + (size_t)r * HEAD_DIM + dq * 64 + n];
    }
    __syncthreads();

    const int tm0 = wave * 16;

    // G = C@B^T
    f32x4 g[4];
#pragma unroll
    for (int j = 0; j < 4; ++j) g[j] = (f32x4)0.f;
#pragma unroll
    for (int kk = 0; kk < 2; ++kk) {
        f16x8 af = *(const f16x8*)&Ct[(tm0 + fr) * PADT + kk * 32 + quad * 8];
#pragma unroll
        for (int j = 0; j < 4; ++j) {
            f16x8 bf = *(const f16x8*)&Bt[(j * 16 + fr) * PADT + kk * 32 + quad * 8];
            g[j] = __builtin_amdgcn_mfma_f32_16x16x32_f16(af, bf, g[j], 0, 0, 0);
        }
    }
    // mask + decay -> Ps (same-wave rows only; no barrier needed)
    {
        int trow = tm0 + quad * 4;
#pragma unroll
        for (int j = 0; j < 4; ++j) {
#pragma unroll
            for (int reg = 0; reg < 4; ++reg) {
                int tt = trow + reg, ss = j * 16 + fr;
                float val = 0.f;
                if (ss <= tt) val = expf(Ahd * (SDs[tt] - SDs[ss])) * g[j][reg];
                Ps[tt * PADT + ss] = f2h(val);
            }
        }
    }

    // Y1 = P @ X ; Y2 = C @ H
    f32x4 ya[4], yb[4];
#pragma unroll
    for (int j = 0; j < 4; ++j) { ya[j] = (f32x4)0.f; yb[j] = (f32x4)0.f; }
#pragma unroll
    for (int kk = 0; kk < 2; ++kk) {
        f16x8 afp = *(const f16x8*)&Ps[(tm0 + fr) * PADT + kk * 32 + quad * 8];
        f16x8 afc = *(const f16x8*)&Ct[(tm0 + fr) * PADT + kk * 32 + quad * 8];
#pragma unroll
        for (int j = 0; j < 4; ++j) {
            f16x8 bx = *(const f16x8*)&XsT[(j * 16 + fr) * PADT + kk * 32 + quad * 8];
            f16x8 bh_ = *(const f16x8*)&Hdn[(j * 16 + fr) * PADT + kk * 32 + quad * 8];
            ya[j] = __builtin_amdgcn_mfma_f32_16x16x32_f16(afp, bx, ya[j], 0, 0, 0);
            yb[j] = __builtin_amdgcn_mfma_f32_16x16x32_f16(afc, bh_, yb[j], 0, 0, 0);
        }
    }

    // epilogue: gate + fp16 store + row sum-of-squares
    const float Dh = Dp[hh];
#pragma unroll
    for (int reg = 0; reg < 4; ++reg) {
        int tt = tm0 + quad * 4 + reg;
        float cum = expf(Ahd * SDs[tt]);
        size_t rowz = (size_t)(m0 + tt) * NPROJ;
        size_t rowy = (size_t)(m0 + tt) * D_INNER + xcol;
        float ss = 0.f;
#pragma unroll
        for (int j = 0; j < 4; ++j) {
            int dd = j * 16 + fr;
            float xv = h2f(XsT[dd * PADT + tt]);
            float z  = zx[rowz + OFF_Z + xcol + dd];
            float yv = ya[j][reg] + cum * yb[j][reg] + Dh * xv;
            float gated = yv * (z / (1.f + expf(-z)));
            ybf[rowy + dd] = f2h(gated);
            ss += gated * gated;
        }
        // reduce across the 16 lanes of this quad (fr dimension)
#pragma unroll
        for (int off = 1; off < 16; off <<= 1) ss += __shfl_xor(ss, off);
        if (fr == 0) atomicAdd(&rowSS[m0 + tt], ss);
    }
}

// ---------------------------------------------------------------------------
extern "C" void kernel_launch(void* const* d_in, const int* in_sizes, int n_in,
                              void* d_out, int out_size, void* d_ws, size_t ws_size,
                              hipStream_t stream) {
    const float* x         = (const float*)d_in[0];
    const float* in_proj_w = (const float*)d_in[1];
    const float* conv_w    = (const float*)d_in[2];
    const float* conv_b    = (const float*)d_in[3];
    const float* A_log     = (const float*)d_in[4];
    const float* D_param   = (const float*)d_in[5];
    const float* dt_bias   = (const float*)d_in[6];
    const float* norm_w    = (const float*)d_in[7];
    const float* out_proj_w= (const float*)d_in[8];
    float* out = (float*)d_out;

    // workspace layout (floats):
    //  zx  @0         8,667,136  | later pbuf (2x 2,097,152 fits)
    //  R1  @8667136   2,166,784  | xh(u16) -> wobf_h(u16)
    //  R2  @10833920  4,194,304  | xbf_h(u16) -> ybf(u16)
    //  ab  @15028224     16,384  | csum(256) + rowSS(2048)
    //  R3  @15044608  4,194,304  | wibf_h(u16) -> Sloc(fp16, 8.4MB)
    float* ws  = (float*)d_ws;
    float* zx  = ws;
    float* R1  = zx + 8667136;
    float* R2  = R1 + 2166784;
    float* ab  = R2 + 4194304;
    float* R3  = ab + 16384;

    u16*  xh     = (u16*)R1;
    u16*  wobf_h = (u16*)R1;     // reuses xh region after last xh read
    u16*  xbf_h  = (u16*)R2;
    u16*  ybf    = (u16*)R2;     // reuses xbf region after GEMM1
    float* csum  = ab;
    float* rowSS = ab + 2048;
    u16*  wibf_h = (u16*)R3;
    u16*  Sloc   = (u16*)R3;     // fp16 states; reuses wibf region after GEMM1
    float* pbuf  = zx;

    // 0) zero rowSS (8 KB) + casts for GEMM1
    hipMemsetAsync(rowSS, 0, M_ROWS * sizeof(float), stream);
    {
        int n0 = M_ROWS * DIM;              // 2,097,152
        int n1 = NPROJ * DIM;               // 4,333,568
        cast2_kernel<<<(n0 + n1) / 1024, 256, 0, stream>>>(
            x, xbf_h, n0, in_proj_w, wibf_h, n1);
    }

    // 1) zxBCdt = x @ in_proj_w^T  (2048 x 4232, K=1024)
    gemm_mfma1<128><<<dim3(NPROJ_PAD / 128, M_ROWS / 128, 1), 256, 0, stream>>>(
        xbf_h, wibf_h, zx, DIM, NPROJ, NPROJ, NPROJ, 0);

    // 2) conv + silu -> xh (fp16)
    conv_silu_kernel<<<(M_ROWS * D_INNER) / 256, 256, 0, stream>>>(
        zx, conv_w, conv_b, xh);

    // 3) SSD chunked scan (fp16 states)
    scan_state_mfma<<<BATCH * N_HEADS * N_CHUNK * 4, 256, 0, stream>>>(
        zx, xh, dt_bias, A_log, Sloc, csum);
    scan_combine2<<<BATCH * N_HEADS * 32, 256, 0, stream>>>(
        csum, A_log, (u32*)Sloc);
    scan_ycorr_mfma<<<BATCH * N_HEADS * N_CHUNK * 4, 256, 0, stream>>>(
        zx, xh, dt_bias, A_log, D_param, Sloc, ybf, rowSS);

    // 4) fp16 cast for GEMM2 weights, norm_w folded in
    cast_hn_kernel<<<(DIM * D_INNER) / 1024, 256, 0, stream>>>(
        out_proj_w, norm_w, wobf_h, DIM * D_INNER);

    // 5) out_pre = y_gated @ (W*nw)^T  (2048 x 1024, K=2048), BN=64, split-K=2
    gemm_mfma1<64><<<dim3(DIM / 64, M_ROWS / 128, 2), 256, 0, stream>>>(
        ybf, wobf_h, pbuf, D_INNER, DIM, DIM, DIM,
        (size_t)M_ROWS * DIM);

    // 6) reduce partials + apply per-row RMS scale -> out
    reduce2rms_kernel<<<(M_ROWS * DIM) / 1024, 256, 0, stream>>>(
        pbuf, rowSS, out, M_ROWS * DIM);
}

// Round 7
// 196.337 us; speedup vs baseline: 1.4300x; 1.0350x over previous
//
#include <hip/hip_runtime.h>
#include <hip/hip_bf16.h>
#include <math.h>

#define DIM      1024
#define D_STATE  64
#define D_CONV   4
#define N_HEADS  8
#define D_INNER  2048
#define HEAD_DIM 256
#define NPROJ    4232      // 2048 + 2048 + 8 + 64 + 64
#define BATCH    2
#define SEQ      1024
#define M_ROWS   (BATCH * SEQ)   // 2048
#define OFF_Z    0
#define OFF_XC   2048
#define OFF_DT   4096
#define OFF_B    4104
#define OFF_C    4168

#define CHUNK    64
#define N_CHUNK  (SEQ / CHUNK)    // 16
#define STATE_PER_BH (HEAD_DIM * D_STATE)   // 16384 elems

#define NPROJ_PAD 4352            // 34 * 128 (GEMM1 grid only; B rows guarded)
#define PADT 72                   // padded u16 row pitch for 64-wide LDS tiles

typedef unsigned short u16;
typedef unsigned int   u32;
typedef _Float16 f16x8 __attribute__((ext_vector_type(8)));
typedef float    f32x4 __attribute__((ext_vector_type(4)));

__device__ __forceinline__ u16 f2h(float f) {
    _Float16 h = (_Float16)f;
    return __builtin_bit_cast(u16, h);
}
__device__ __forceinline__ float h2f(u16 u) {
    return (float)__builtin_bit_cast(_Float16, u);
}

__device__ __forceinline__ void load_lds16(const void* g, void* l) {
    __builtin_amdgcn_global_load_lds((const __attribute__((address_space(1))) unsigned int*)g,
                                     (__attribute__((address_space(3))) unsigned int*)l,
                                     16, 0, 0);
}

// fast softplus: __logf/__expf (v_exp/v_log based); error ~1e-6 abs, far
// below the fp16 noise floor of the scan path.
__device__ __forceinline__ float softplus_f(float v) {
    return (v > 20.f) ? v : __logf(1.f + __expf(v));
}

// ---------------------------------------------------------------------------
// merged cast: x and in_proj_w -> single fp16.
// ---------------------------------------------------------------------------
__global__ __launch_bounds__(256) void cast2_kernel(
        const float* __restrict__ s0, u16* __restrict__ h0, int n0,
        const float* __restrict__ s1, u16* __restrict__ h1, int n1) {
    int i4 = (blockIdx.x * 256 + threadIdx.x) * 4;
    const float* src; u16* dst;
    if (i4 < n0) {
        src = s0; dst = h0;
    } else {
        i4 -= n0;
        if (i4 >= n1) return;
        src = s1; dst = h1;
    }
    float4 v = *(const float4*)&src[i4];
    ushort4 h;
    h.x = f2h(v.x); h.y = f2h(v.y); h.z = f2h(v.z); h.w = f2h(v.w);
    *(ushort4*)&dst[i4] = h;
}

// out_proj_w cast with norm_w folded in (diagonal commutes with row scaling)
__global__ __launch_bounds__(256) void cast_hn_kernel(const float* __restrict__ src,
                                                      const float* __restrict__ nw,
                                                      u16* __restrict__ hi, int n) {
    int i4 = (blockIdx.x * 256 + threadIdx.x) * 4;
    if (i4 >= n) return;
    float4 v = *(const float4*)&src[i4];
    int c = i4 & (D_INNER - 1);
    ushort4 h;
    h.x = f2h(v.x * nw[c]);
    h.y = f2h(v.y * nw[c + 1]);
    h.z = f2h(v.z * nw[c + 2]);
    h.w = f2h(v.w * nw[c + 3]);
    *(ushort4*)&hi[i4] = h;
}

// ---------------------------------------------------------------------------
// fp16 MFMA GEMM: C = A @ B^T, fp32 accum (m97 structure).
// BM=128 x BN tile, BK=32, 256 thr (2x2 waves).
// ---------------------------------------------------------------------------
template<int BN>
__global__ __launch_bounds__(256) void gemm_mfma1(const u16* __restrict__ Ah,
                                                  const u16* __restrict__ Bh,
                                                  float* __restrict__ C,
                                                  int K, int ldc, int Nstore,
                                                  int NrowsB, size_t zstride) {
    __shared__ u16 As[128 * 32];
    __shared__ u16 Bs[BN * 32];

    const int tid  = threadIdx.x;
    const int wave = tid >> 6;
    const int lane = tid & 63;
    const int fr   = lane & 15;
    const int kc   = lane >> 4;
    const int m0   = blockIdx.y * 128;
    const int n0   = blockIdx.x * BN;
    const int wm   = (wave & 1) * 64;
    const int wn   = (wave >> 1) * (BN / 2);

    const int kPer = K / gridDim.z;
    const int kBeg = blockIdx.z * kPer;
    C += (size_t)blockIdx.z * zstride;

    f32x4 acc[4][BN / 32];
#pragma unroll
    for (int i = 0; i < 4; ++i)
#pragma unroll
        for (int j = 0; j < BN / 32; ++j) acc[i][j] = (f32x4)0.f;

    for (int k0 = kBeg; k0 < kBeg + kPer; k0 += 32) {
        __syncthreads();
#pragma unroll
        for (int q = 0; q < 2; ++q) {
            int s = wave * 128 + q * 64 + lane;
            int r = s >> 2, pc = s & 3;
            int gc = pc ^ ((r >> 1) & 3);
            size_t goff = (size_t)(m0 + r) * K + k0 + gc * 8;
            load_lds16(Ah + goff, &As[(wave * 128 + q * 64) * 8]);
        }
#pragma unroll
        for (int q = 0; q < BN / 64; ++q) {
            int s = wave * BN + q * 64 + lane;
            int r = s >> 2, pc = s & 3;
            int gc = pc ^ ((r >> 1) & 3);
            if (n0 + r < NrowsB) {   // OOB rows: stale LDS, results never stored
                size_t goff = (size_t)(n0 + r) * K + k0 + gc * 8;
                load_lds16(Bh + goff, &Bs[(wave * BN + q * 64) * 8]);
            }
        }
        __syncthreads();

        f16x8 af[4];
#pragma unroll
        for (int i = 0; i < 4; ++i) {
            int r = wm + i * 16 + fr;
            int off = r * 32 + (kc ^ ((r >> 1) & 3)) * 8;
            af[i] = *(const f16x8*)&As[off];
        }
        f16x8 bf[BN / 32];
#pragma unroll
        for (int j = 0; j < BN / 32; ++j) {
            int r = wn + j * 16 + fr;
            int off = r * 32 + (kc ^ ((r >> 1) & 3)) * 8;
            bf[j] = *(const f16x8*)&Bs[off];
        }
#pragma unroll
        for (int i = 0; i < 4; ++i)
#pragma unroll
            for (int j = 0; j < BN / 32; ++j)
                acc[i][j] = __builtin_amdgcn_mfma_f32_16x16x32_f16(af[i], bf[j], acc[i][j], 0, 0, 0);
    }

    // epilogue: C/D layout col=lane&15, row=(lane>>4)*4+reg  [m89/m91]
    const int row0 = m0 + wm + (lane >> 4) * 4;
    const int colb = n0 + wn + fr;
#pragma unroll
    for (int i = 0; i < 4; ++i)
#pragma unroll
        for (int j = 0; j < BN / 32; ++j) {
            int col = colb + j * 16;
            if (col < Nstore) {
#pragma unroll
                for (int t = 0; t < 4; ++t)
                    C[(size_t)(row0 + i * 16 + t) * ldc + col] = acc[i][j][t];
            }
        }
}

// ---------------------------------------------------------------------------
// split-K=2 reduce + per-row RMS scale (rowSS = sum of squares of gated y)
// ---------------------------------------------------------------------------
__global__ __launch_bounds__(256) void reduce2rms_kernel(const float* __restrict__ p,
                                                         const float* __restrict__ rowSS,
                                                         float* __restrict__ out, int n) {
    int i4 = (blockIdx.x * 256 + threadIdx.x) * 4;
    int m = i4 >> 10;                         // DIM=1024 cols per row
    float scale = rsqrtf(rowSS[m] * (1.f / (float)D_INNER) + 1e-6f);
    float4 a = *(const float4*)&p[i4];
    float4 b = *(const float4*)&p[(size_t)n + i4];
    *(float4*)&out[i4] = make_float4((a.x + b.x) * scale, (a.y + b.y) * scale,
                                     (a.z + b.z) * scale, (a.w + b.w) * scale);
}

// ---------------------------------------------------------------------------
// depthwise causal conv (k=4) + SiLU -> xh (fp16)
// ---------------------------------------------------------------------------
__global__ __launch_bounds__(256) void conv_silu_kernel(const float* __restrict__ zx,
                                                        const float* __restrict__ conv_w,
                                                        const float* __restrict__ conv_b,
                                                        u16* __restrict__ xh) {
    int idx = blockIdx.x * 256 + threadIdx.x;
    int c = idx & (D_INNER - 1);
    int m = idx >> 11;
    int l = m & (SEQ - 1);
    float acc = conv_b[c];
#pragma unroll
    for (int k = 0; k < D_CONV; ++k) {
        int lj = l + k - (D_CONV - 1);
        if (lj >= 0)
            acc = fmaf(zx[(size_t)(m + k - (D_CONV - 1)) * NPROJ + OFF_XC + c],
                       conv_w[c * D_CONV + k], acc);
    }
    xh[idx] = f2h(acc / (1.f + __expf(-acc)));
}

// ---------------------------------------------------------------------------
// PASS 1 (states only): per (b,h,chunk,dq): S_c = (w2*B)^T @ X  -> Sloc (fp16).
// dq==0 block also writes csum[bh][c] = sum of dt over the chunk (SD63).
// ---------------------------------------------------------------------------
__global__ __launch_bounds__(256) void scan_state_mfma(const float* __restrict__ zx,
                                                       const u16* __restrict__ xh,
                                                       const float* __restrict__ dt_bias,
                                                       const float* __restrict__ A_log,
                                                       u16* __restrict__ Sloc,
                                                       float* __restrict__ csum) {
    const int blk = blockIdx.x;                 // 0..1023
    const int dq = blk & 3;
    const int c  = (blk >> 2) & (N_CHUNK - 1);
    const int bh = blk >> 6;
    const int hh = bh & (N_HEADS - 1);
    const int b  = bh >> 3;
    const int t    = threadIdx.x;
    const int wave = t >> 6;
    const int lane = t & 63;
    const int fr   = lane & 15;
    const int quad = lane >> 4;

    __shared__ float SDs[64];
    __shared__ u16 BwT[64 * PADT];
    __shared__ u16 XsT[64 * PADT];

    const int m0   = b * SEQ + c * CHUNK;
    const int xcol = hh * HEAD_DIM + dq * 64;
    const float Ahd = -__expf(A_log[hh]);
    const float dtb = dt_bias[hh];

    if (t < 64) {
        float d = softplus_f(zx[(size_t)(m0 + t) * NPROJ + OFF_DT + hh] + dtb);
#pragma unroll
        for (int off = 1; off < 64; off <<= 1) {
            float o = __shfl_up(d, off);
            if (lane >= off) d += o;
        }
        SDs[t] = d;
    }
    __syncthreads();
    const float SD63 = SDs[63];
    if (dq == 0 && t == 0) csum[bh * N_CHUNK + c] = SD63;

#pragma unroll
    for (int i = 0; i < 16; ++i) {
        int idx = t + i * 256;
        int r = idx >> 6, n = idx & 63;
        float bv = zx[(size_t)(m0 + r) * NPROJ + OFF_B + n];
        float w2 = __expf(Ahd * (SD63 - SDs[r]));
        BwT[n * PADT + r] = f2h(bv * w2);
        XsT[n * PADT + r] = xh[(size_t)(m0 + r) * D_INNER + xcol + n];
    }
    __syncthreads();

    const int tm0 = wave * 16;
    f32x4 sa[4];
#pragma unroll
    for (int j = 0; j < 4; ++j) sa[j] = (f32x4)0.f;
#pragma unroll
    for (int kk = 0; kk < 2; ++kk) {
        f16x8 af = *(const f16x8*)&BwT[(tm0 + fr) * PADT + kk * 32 + quad * 8];
#pragma unroll
        for (int j = 0; j < 4; ++j) {
            f16x8 bf = *(const f16x8*)&XsT[(j * 16 + fr) * PADT + kk * 32 + quad * 8];
            sa[j] = __builtin_amdgcn_mfma_f32_16x16x32_f16(af, bf, sa[j], 0, 0, 0);
        }
    }
    size_t sbase = (size_t)(bh * N_CHUNK + c) * STATE_PER_BH;
#pragma unroll
    for (int j = 0; j < 4; ++j)
#pragma unroll
        for (int reg = 0; reg < 4; ++reg) {
            int nn = tm0 + quad * 4 + reg;
            int dd = j * 16 + fr;
            Sloc[sbase + (size_t)nn * HEAD_DIM + dq * 64 + dd] = f2h(sa[j][reg]);
        }
}

// ---------------------------------------------------------------------------
// PASS 2: inter-chunk recurrence in place on fp16 Sloc (u32 = 2 packed fp16).
// ---------------------------------------------------------------------------
__global__ __launch_bounds__(256) void scan_combine2(const float* __restrict__ csum,
                                                     const float* __restrict__ A_log,
                                                     u32* __restrict__ Sl) {
    const int blk = blockIdx.x;               // 0..511
    const int seg = blk & 31;                 // 32 segs x 256 u32 = 8192 u32/chunk
    const int bh  = blk >> 5;
    const int hh  = bh & (N_HEADS - 1);
    const int t   = threadIdx.x;

    __shared__ float PS[N_CHUNK];
    if (t < N_CHUNK) {
        float Ahd = -__expf(A_log[hh]);
        PS[t] = __expf(Ahd * csum[bh * N_CHUNK + t]);
    }
    __syncthreads();

    const int HPC = STATE_PER_BH / 2;         // 8192 u32 per chunk
    size_t base = (size_t)bh * N_CHUNK * HPC + seg * 256 + t;
    u32 Sv[N_CHUNK];
#pragma unroll
    for (int c = 0; c < N_CHUNK; ++c)
        Sv[c] = Sl[base + (size_t)c * HPC];
    float H0 = 0.f, H1 = 0.f;
#pragma unroll
    for (int c = 0; c < N_CHUNK; ++c) {
        Sl[base + (size_t)c * HPC] = ((u32)f2h(H1) << 16) | (u32)f2h(H0);
        float P = PS[c];
        H0 = fmaf(P, H0, h2f((u16)(Sv[c] & 0xffffu)));
        H1 = fmaf(P, H1, h2f((u16)(Sv[c] >> 16)));
    }
}

// ---------------------------------------------------------------------------
// PASS 3 (fused): per (b,h,chunk,dq):
//   G = C@B^T; P = mask*decay*G; Y = P@X + cum*(C@H) + D*x;
//   ybf = fp16(Y * silu(z)); rowSS += per-row sum of squares.
// LDS plan: Ps aliases Bt (Bt dead after G; barrier separates). 37.2 KB ->
// 4 blocks/CU, grid 1024 = exactly one resident round.
// T14: Hini loads issued to regs up-front; Hdn LDS writes after G barrier.
// ---------------------------------------------------------------------------
__global__ __launch_bounds__(256) void scan_ycorr_mfma(const float* __restrict__ zx,
                                                       const u16* __restrict__ xh,
                                                       const float* __restrict__ dt_bias,
                                                       const float* __restrict__ A_log,
                                                       const float* __restrict__ Dp,
                                                       const u16* __restrict__ Hini,
                                                       u16* __restrict__ ybf,
                                                       float* __restrict__ rowSS) {
    const int blk = blockIdx.x;                 // 0..1023
    const int dq = blk & 3;
    const int c  = (blk >> 2) & (N_CHUNK - 1);
    const int bh = blk >> 6;
    const int hh = bh & (N_HEADS - 1);
    const int b  = bh >> 3;
    const int t    = threadIdx.x;
    const int wave = t >> 6;
    const int lane = t & 63;
    const int fr   = lane & 15;
    const int quad = lane >> 4;

    __shared__ float SDs[64];
    __shared__ u16 Ct  [64 * PADT];
    __shared__ u16 BtPs[64 * PADT];             // Bt during G-phase, Ps after
    __shared__ u16 XsT [64 * PADT];
    __shared__ u16 Hdn [64 * PADT];

    const int m0   = b * SEQ + c * CHUNK;
    const int xcol = hh * HEAD_DIM + dq * 64;
    const float Ahd = -__expf(A_log[hh]);
    const float dtb = dt_bias[hh];

    if (t < 64) {
        float d = softplus_f(zx[(size_t)(m0 + t) * NPROJ + OFF_DT + hh] + dtb);
#pragma unroll
        for (int off = 1; off < 64; off <<= 1) {
            float o = __shfl_up(d, off);
            if (lane >= off) d += o;
        }
        SDs[t] = d;
    }

    // T14: issue H loads first (latency hides under staging + G phase)
    size_t hbase = (size_t)(bh * N_CHUNK + c) * STATE_PER_BH;
    u16 hreg[16];
#pragma unroll
    for (int i = 0; i < 16; ++i) {
        int idx = t + i * 256;
        int r = idx >> 6, n = idx & 63;
        hreg[i] = Hini[hbase + (size_t)r * HEAD_DIM + dq * 64 + n];
    }

#pragma unroll
    for (int i = 0; i < 16; ++i) {
        int idx = t + i * 256;
        int r = idx >> 6, n = idx & 63;
        size_t rowz = (size_t)(m0 + r) * NPROJ;
        BtPs[r * PADT + n] = f2h(zx[rowz + OFF_B + n]);
        Ct[r * PADT + n]   = f2h(zx[rowz + OFF_C + n]);
        XsT[n * PADT + r]  = xh[(size_t)(m0 + r) * D_INNER + xcol + n];
    }
    __syncthreads();

    const int tm0 = wave * 16;

    // G = C@B^T
    f32x4 g[4];
#pragma unroll
    for (int j = 0; j < 4; ++j) g[j] = (f32x4)0.f;
#pragma unroll
    for (int kk = 0; kk < 2; ++kk) {
        f16x8 af = *(const f16x8*)&Ct[(tm0 + fr) * PADT + kk * 32 + quad * 8];
#pragma unroll
        for (int j = 0; j < 4; ++j) {
            f16x8 bf = *(const f16x8*)&BtPs[(j * 16 + fr) * PADT + kk * 32 + quad * 8];
            g[j] = __builtin_amdgcn_mfma_f32_16x16x32_f16(af, bf, g[j], 0, 0, 0);
        }
    }
    __syncthreads();                            // all waves done reading Bt

    // mask + decay -> Ps (into Bt's storage); Hdn writes from hreg
    {
        int trow = tm0 + quad * 4;
#pragma unroll
        for (int j = 0; j < 4; ++j) {
#pragma unroll
            for (int reg = 0; reg < 4; ++reg) {
                int tt = trow + reg, ss = j * 16 + fr;
                float val = 0.f;
                if (ss <= tt) val = __expf(Ahd * (SDs[tt] - SDs[ss])) * g[j][reg];
                BtPs[tt * PADT + ss] = f2h(val);
            }
        }
    }
#pragma unroll
    for (int i = 0; i < 16; ++i) {
        int idx = t + i * 256;
        int r = idx >> 6, n = idx & 63;
        Hdn[n * PADT + r] = hreg[i];
    }
    __syncthreads();                            // Hdn visible to all waves

    // Y1 = P @ X ; Y2 = C @ H
    f32x4 ya[4], yb[4];
#pragma unroll
    for (int j = 0; j < 4; ++j) { ya[j] = (f32x4)0.f; yb[j] = (f32x4)0.f; }
#pragma unroll
    for (int kk = 0; kk < 2; ++kk) {
        f16x8 afp = *(const f16x8*)&BtPs[(tm0 + fr) * PADT + kk * 32 + quad * 8];
        f16x8 afc = *(const f16x8*)&Ct[(tm0 + fr) * PADT + kk * 32 + quad * 8];
#pragma unroll
        for (int j = 0; j < 4; ++j) {
            f16x8 bx = *(const f16x8*)&XsT[(j * 16 + fr) * PADT + kk * 32 + quad * 8];
            f16x8 bh_ = *(const f16x8*)&Hdn[(j * 16 + fr) * PADT + kk * 32 + quad * 8];
            ya[j] = __builtin_amdgcn_mfma_f32_16x16x32_f16(afp, bx, ya[j], 0, 0, 0);
            yb[j] = __builtin_amdgcn_mfma_f32_16x16x32_f16(afc, bh_, yb[j], 0, 0, 0);
        }
    }

    // epilogue: gate + fp16 store + row sum-of-squares
    const float Dh = Dp[hh];
#pragma unroll
    for (int reg = 0; reg < 4; ++reg) {
        int tt = tm0 + quad * 4 + reg;
        float cum = __expf(Ahd * SDs[tt]);
        size_t rowz = (size_t)(m0 + tt) * NPROJ;
        size_t rowy = (size_t)(m0 + tt) * D_INNER + xcol;
        float ss = 0.f;
#pragma unroll
        for (int j = 0; j < 4; ++j) {
            int dd = j * 16 + fr;
            float xv = h2f(XsT[dd * PADT + tt]);
            float z  = zx[rowz + OFF_Z + xcol + dd];
            float yv = ya[j][reg] + cum * yb[j][reg] + Dh * xv;
            float gated = yv * (z / (1.f + __expf(-z)));
            ybf[rowy + dd] = f2h(gated);
            ss += gated * gated;
        }
        // reduce across the 16 lanes of this quad (fr dimension)
#pragma unroll
        for (int off = 1; off < 16; off <<= 1) ss += __shfl_xor(ss, off);
        if (fr == 0) atomicAdd(&rowSS[m0 + tt], ss);
    }
}

// ---------------------------------------------------------------------------
extern "C" void kernel_launch(void* const* d_in, const int* in_sizes, int n_in,
                              void* d_out, int out_size, void* d_ws, size_t ws_size,
                              hipStream_t stream) {
    const float* x         = (const float*)d_in[0];
    const float* in_proj_w = (const float*)d_in[1];
    const float* conv_w    = (const float*)d_in[2];
    const float* conv_b    = (const float*)d_in[3];
    const float* A_log     = (const float*)d_in[4];
    const float* D_param   = (const float*)d_in[5];
    const float* dt_bias   = (const float*)d_in[6];
    const float* norm_w    = (const float*)d_in[7];
    const float* out_proj_w= (const float*)d_in[8];
    float* out = (float*)d_out;

    // workspace layout (floats):
    //  zx  @0         8,667,136  | later pbuf (2x 2,097,152 fits)
    //  R1  @8667136   2,166,784  | xh(u16) -> wobf_h(u16)
    //  R2  @10833920  4,194,304  | xbf_h(u16) -> ybf(u16)
    //  ab  @15028224     16,384  | csum(256) + rowSS(2048)
    //  R3  @15044608  4,194,304  | wibf_h(u16) -> Sloc(fp16, 8.4MB)
    float* ws  = (float*)d_ws;
    float* zx  = ws;
    float* R1  = zx + 8667136;
    float* R2  = R1 + 2166784;
    float* ab  = R2 + 4194304;
    float* R3  = ab + 16384;

    u16*  xh     = (u16*)R1;
    u16*  wobf_h = (u16*)R1;     // reuses xh region after last xh read
    u16*  xbf_h  = (u16*)R2;
    u16*  ybf    = (u16*)R2;     // reuses xbf region after GEMM1
    float* csum  = ab;
    float* rowSS = ab + 2048;
    u16*  wibf_h = (u16*)R3;
    u16*  Sloc   = (u16*)R3;     // fp16 states; reuses wibf region after GEMM1
    float* pbuf  = zx;

    // 0) zero rowSS (8 KB) + casts for GEMM1
    hipMemsetAsync(rowSS, 0, M_ROWS * sizeof(float), stream);
    {
        int n0 = M_ROWS * DIM;              // 2,097,152
        int n1 = NPROJ * DIM;               // 4,333,568
        cast2_kernel<<<(n0 + n1) / 1024, 256, 0, stream>>>(
            x, xbf_h, n0, in_proj_w, wibf_h, n1);
    }

    // 1) zxBCdt = x @ in_proj_w^T  (2048 x 4232, K=1024)
    gemm_mfma1<128><<<dim3(NPROJ_PAD / 128, M_ROWS / 128, 1), 256, 0, stream>>>(
        xbf_h, wibf_h, zx, DIM, NPROJ, NPROJ, NPROJ, 0);

    // 2) conv + silu -> xh (fp16)
    conv_silu_kernel<<<(M_ROWS * D_INNER) / 256, 256, 0, stream>>>(
        zx, conv_w, conv_b, xh);

    // 3) SSD chunked scan (fp16 states)
    scan_state_mfma<<<BATCH * N_HEADS * N_CHUNK * 4, 256, 0, stream>>>(
        zx, xh, dt_bias, A_log, Sloc, csum);
    scan_combine2<<<BATCH * N_HEADS * 32, 256, 0, stream>>>(
        csum, A_log, (u32*)Sloc);
    scan_ycorr_mfma<<<BATCH * N_HEADS * N_CHUNK * 4, 256, 0, stream>>>(
        zx, xh, dt_bias, A_log, D_param, Sloc, ybf, rowSS);

    // 4) fp16 cast for GEMM2 weights, norm_w folded in
    cast_hn_kernel<<<(DIM * D_INNER) / 1024, 256, 0, stream>>>(
        out_proj_w, norm_w, wobf_h, DIM * D_INNER);

    // 5) out_pre = y_gated @ (W*nw)^T  (2048 x 1024, K=2048), BN=64, split-K=2
    gemm_mfma1<64><<<dim3(DIM / 64, M_ROWS / 128, 2), 256, 0, stream>>>(
        ybf, wobf_h, pbuf, D_INNER, DIM, DIM, DIM,
        (size_t)M_ROWS * DIM);

    // 6) reduce partials + apply per-row RMS scale -> out
    reduce2rms_kernel<<<(M_ROWS * DIM) / 1024, 256, 0, stream>>>(
        pbuf, rowSS, out, M_ROWS * DIM);
}